// Round 1
// baseline (203363.489 us; speedup 1.0000x reference)
//
#include <hip/hip_runtime.h>
#include <hip/hip_bf16.h>
#include <math.h>

#define HIDN 400
#define G4   1600   // 4*HIDN
#define KK   10
#define UU   64
#define DD   60
#define TT   600
#define BB   64
#define IN1  463    // 3 + 60 + 400
#define IN2  863    // 3 + 60 + 400 + 400
#define FCIN 800
#define FCOUT 121

// ---- d_out offsets (floats), outputs concatenated flat in return order ----
#define PI_OFF    0          // B*T*20   = 768000
#define MU_OFF    768000     // B*T*40   = 1536000
#define SIG_OFF   2304000    // B*T*40   = 1536000
#define RHO_OFF   3840000    // B*T*20   = 768000
#define EOS_OFF   4608000    // B*T      = 38400
#define WF_OFF    4646400    // B*60     = 3840
#define KAPPA_OFF 4650240    // B*10     = 640
#define PHI_OFF   4650880    // B*64     = 4096
#define H0F_OFF   4654976    // B*400    = 25600
#define C0F_OFF   4680576
#define H1F_OFF   4706176
#define C1F_OFF   4731776
// total out = 4757376 floats

// ---- workspace offsets (floats) ----
#define WS_H1   0            // B*T*400 = 15360000
#define WS_WT   15360000     // B*T*60  = 2304000
#define WS_H2   17664000     // B*T*400 = 15360000
#define WS_WC1  33024000     // 463*1600 = 740800
#define WS_WC2  33764800     // 863*1600 = 1380800
#define WS_WFCT 35145600     // 800*121  = 96800
// total ws = 35242400 floats = 141 MB

__device__ __forceinline__ float sigm(float x){ return 1.0f/(1.0f + expf(-x)); }

// Build combined transposed weight (K rows, 1600 cols): row k<63 from W_ih1, else W_hh1.
__global__ void prep_w1(const float* __restrict__ Wih1, const float* __restrict__ Whh1,
                        float* __restrict__ WC1){
  int idx = blockIdx.x*blockDim.x + threadIdx.x;
  if (idx >= IN1*G4) return;
  int k = idx / G4, g = idx - k*G4;
  WC1[idx] = (k < 63) ? Wih1[g*63 + k] : Whh1[g*HIDN + (k-63)];
}
__global__ void prep_w2(const float* __restrict__ Wih2, const float* __restrict__ Whh2,
                        float* __restrict__ WC2){
  int idx = blockIdx.x*blockDim.x + threadIdx.x;
  if (idx >= IN2*G4) return;
  int k = idx / G4, g = idx - k*G4;
  WC2[idx] = (k < IN1) ? Wih2[g*IN1 + k] : Whh2[g*HIDN + (k-IN1)];
}
__global__ void prep_wfc(const float* __restrict__ Wfc, float* __restrict__ WfcT){
  int idx = blockIdx.x*blockDim.x + threadIdx.x;
  if (idx >= FCIN*FCOUT) return;
  int k = idx / FCOUT, j = idx - k*FCOUT;
  WfcT[idx] = Wfc[j*FCIN + k];
}

// ---------------- Pass 1: LSTM1 + attention window, one block per batch ----------------
__global__ __launch_bounds__(1024) void pass1_kernel(
    const float* __restrict__ strokes, const float* __restrict__ onehots,
    const float* __restrict__ tmask,   const float* __restrict__ WC1,
    const float* __restrict__ b1,      const float* __restrict__ Wwin,
    const float* __restrict__ bwin,
    float* __restrict__ H1, float* __restrict__ Wt, float* __restrict__ outp)
{
  const int b = blockIdx.x;
  const int tid = threadIdx.x;
  __shared__ float xin[IN1+1];       // [x(3), w(60), h(400)]
  __shared__ float hC[HIDN], cC[HIDN];
  __shared__ float gates[G4];
  __shared__ float pw[3*KK];         // exp'd: alpha(10), beta(10), kappa_inc(10)
  __shared__ float kap[KK];
  __shared__ float phi[UU];

  if (tid < HIDN){ hC[tid]=0.f; cC[tid]=0.f; }
  if (tid < KK) kap[tid]=0.f;
  if (tid < DD) xin[3+tid] = onehots[(b*UU + 0)*DD + tid];   // w_init = onehots[:,0,:]
  __syncthreads();

  const int g0 = tid;
  const int g1 = tid + 1024;
  const bool two = (g1 < G4);

  for (int t=0; t<TT; ++t){
    if (tid < 3)    xin[tid]      = strokes[(b*TT + t)*3 + tid];
    if (tid < HIDN) xin[63 + tid] = hC[tid];
    __syncthreads();

    // gates = b1 + [x,w,h] @ WC1  (coalesced over g, xin broadcast from LDS)
    {
      float a0 = b1[g0];
      float a1 = two ? b1[g1] : 0.f;
      #pragma unroll 4
      for (int k=0; k<IN1; ++k){
        float x = xin[k];
        const float* __restrict__ r = WC1 + (size_t)k*G4;
        a0 = fmaf(x, r[g0], a0);
        if (two) a1 = fmaf(x, r[g1], a1);
      }
      gates[g0] = a0;
      if (two) gates[g1] = a1;
    }
    __syncthreads();

    // LSTM pointwise (split order: i, f, g, o)
    if (tid < HIDN){
      float gi = gates[tid], gf = gates[HIDN+tid], gg = gates[2*HIDN+tid], go = gates[3*HIDN+tid];
      float cn = sigm(gf)*cC[tid] + sigm(gi)*tanhf(gg);
      float hn = sigm(go)*tanhf(cn);
      cC[tid]=cn; hC[tid]=hn;
      H1[((size_t)(b*TT + t))*HIDN + tid] = hn;
    }
    __syncthreads();

    // window params: p = exp(h @ W_win^T + b_win), one wave per output
    {
      const int wid = tid >> 6, lane = tid & 63;
      for (int j = wid; j < 3*KK; j += 16){
        float s = 0.f;
        for (int k = lane; k < HIDN; k += 64) s += hC[k]*Wwin[j*HIDN + k];
        for (int off = 32; off > 0; off >>= 1) s += __shfl_down(s, off);
        if (lane == 0) pw[j] = expf(s + bwin[j]);
      }
    }
    __syncthreads();
    if (tid < KK) kap[tid] += pw[2*KK + tid];
    __syncthreads();

    // phi[u] = sum_k alpha_k * exp(-beta_k * (kappa_k - u)^2), masked
    if (tid < UU){
      float u = (float)tid, s = 0.f;
      #pragma unroll
      for (int k=0;k<KK;++k){ float d = kap[k]-u; s = fmaf(pw[k], expf(-pw[KK+k]*d*d), s); }
      s *= tmask[b*UU + tid];
      phi[tid] = s;
      if (t == TT-1) outp[PHI_OFF + b*UU + tid] = s;
    }
    __syncthreads();

    // w[d] = sum_u phi[u] * onehots[b,u,d]
    if (tid < DD){
      float s = 0.f;
      for (int u=0; u<UU; ++u) s = fmaf(phi[u], onehots[(b*UU + u)*DD + tid], s);
      xin[3+tid] = s;                                  // next step's w
      Wt[((size_t)(b*TT + t))*DD + tid] = s;           // attn_out at this step
    }
    __syncthreads();
  }

  if (tid < DD)  outp[WF_OFF    + b*DD + tid] = xin[3+tid];
  if (tid < KK)  outp[KAPPA_OFF + b*KK + tid] = kap[tid];
  if (tid < HIDN){
    outp[H0F_OFF + b*HIDN + tid] = hC[tid];
    outp[C0F_OFF + b*HIDN + tid] = cC[tid];
  }
}

// ---------------- Pass 2: LSTM2, one block per batch ----------------
__global__ __launch_bounds__(1024) void pass2_kernel(
    const float* __restrict__ strokes, const float* __restrict__ Wt,
    const float* __restrict__ H1, const float* __restrict__ WC2,
    const float* __restrict__ b2,
    float* __restrict__ H2, float* __restrict__ outp)
{
  const int b = blockIdx.x;
  const int tid = threadIdx.x;
  __shared__ float xin[IN2+1];   // [x(3), w(60), h1(400), h(400)]
  __shared__ float hC[HIDN], cC[HIDN];
  __shared__ float gates[G4];
  if (tid < HIDN){ hC[tid]=0.f; cC[tid]=0.f; }
  __syncthreads();
  const int g0 = tid, g1 = tid + 1024;
  const bool two = (g1 < G4);

  for (int t=0; t<TT; ++t){
    const size_t pos = (size_t)(b*TT + t);
    if (tid < 3)   xin[tid]     = strokes[pos*3 + tid];
    if (tid < DD)  xin[3+tid]   = Wt[pos*DD + tid];
    if (tid < HIDN){
      xin[63 + tid]  = H1[pos*HIDN + tid];
      xin[IN1 + tid] = hC[tid];
    }
    __syncthreads();

    {
      float a0 = b2[g0];
      float a1 = two ? b2[g1] : 0.f;
      #pragma unroll 4
      for (int k=0; k<IN2; ++k){
        float x = xin[k];
        const float* __restrict__ r = WC2 + (size_t)k*G4;
        a0 = fmaf(x, r[g0], a0);
        if (two) a1 = fmaf(x, r[g1], a1);
      }
      gates[g0] = a0;
      if (two) gates[g1] = a1;
    }
    __syncthreads();

    if (tid < HIDN){
      float gi = gates[tid], gf = gates[HIDN+tid], gg = gates[2*HIDN+tid], go = gates[3*HIDN+tid];
      float cn = sigm(gf)*cC[tid] + sigm(gi)*tanhf(gg);
      float hn = sigm(go)*tanhf(cn);
      cC[tid]=cn; hC[tid]=hn;
      H2[pos*HIDN + tid] = hn;
    }
    __syncthreads();
  }
  if (tid < HIDN){
    outp[H1F_OFF + b*HIDN + tid] = hC[tid];
    outp[C1F_OFF + b*HIDN + tid] = cC[tid];
  }
}

// ---------------- Final FC + heads: 8 positions per block ----------------
__global__ __launch_bounds__(128) void fc_kernel(
    const float* __restrict__ H1, const float* __restrict__ H2,
    const float* __restrict__ WfcT, const float* __restrict__ bfc,
    float* __restrict__ outp)
{
  const int tile = blockIdx.x;      // BB*TT/8 = 4800 tiles
  const int tid  = threadIdx.x;
  __shared__ float X[8][FCIN];
  __shared__ float PS[8][20];
  const size_t base = (size_t)tile * 8;

  for (int i = tid; i < 8*FCIN; i += 128){
    int p = i / FCIN, k = i - p*FCIN;
    size_t pos = base + p;
    X[p][k] = (k < HIDN) ? H1[pos*HIDN + k] : H2[pos*HIDN + (k - HIDN)];
  }
  __syncthreads();

  if (tid < FCOUT){
    float acc[8];
    float bj = bfc[tid];
    #pragma unroll
    for (int p=0;p<8;++p) acc[p]=bj;
    for (int k=0;k<FCIN;++k){
      float wv = WfcT[k*FCOUT + tid];
      float xk0 = X[0][k];  // broadcast reads, conflict-free
      #pragma unroll
      for (int p=0;p<8;++p) acc[p] = fmaf(X[p][k], wv, acc[p]);
      (void)xk0;
    }
    const int j = tid;
    for (int p=0;p<8;++p){
      size_t pos = base + p;
      float v = acc[p];
      if (j < 40)       outp[MU_OFF  + pos*40 + j]        = v;            // mu
      else if (j < 80)  outp[SIG_OFF + pos*40 + (j-40)]   = v;            // log_sigma (raw)
      else if (j < 100) PS[p][j-80] = v;                                  // pi logits
      else if (j < 120) outp[RHO_OFF + pos*20 + (j-100)]  = tanhf(v);     // rho
      else              outp[EOS_OFF + pos]               = 1.0f/(1.0f + expf(v)); // sigmoid(-v)
    }
  }
  __syncthreads();

  if (tid < 8){
    size_t pos = base + tid;
    float m = -1e30f;
    #pragma unroll
    for (int j=0;j<20;++j) m = fmaxf(m, PS[tid][j]);
    float e[20], s = 0.f;
    #pragma unroll
    for (int j=0;j<20;++j){ e[j] = expf(PS[tid][j]-m); s += e[j]; }
    float inv = 1.0f/s;
    #pragma unroll
    for (int j=0;j<20;++j) outp[PI_OFF + pos*20 + j] = e[j]*inv;
  }
}

extern "C" void kernel_launch(void* const* d_in, const int* in_sizes, int n_in,
                              void* d_out, int out_size, void* d_ws, size_t ws_size,
                              hipStream_t stream){
  (void)in_sizes; (void)n_in; (void)out_size; (void)ws_size;
  const float* strokes = (const float*)d_in[0];
  const float* onehots = (const float*)d_in[1];
  const float* tmask   = (const float*)d_in[2];
  const float* Wih1    = (const float*)d_in[3];
  const float* Whh1    = (const float*)d_in[4];
  const float* b1      = (const float*)d_in[5];
  const float* Wwin    = (const float*)d_in[6];
  const float* bwin    = (const float*)d_in[7];
  const float* Wih2    = (const float*)d_in[8];
  const float* Whh2    = (const float*)d_in[9];
  const float* b2      = (const float*)d_in[10];
  const float* Wfc     = (const float*)d_in[11];
  const float* bfc     = (const float*)d_in[12];

  float* ws   = (float*)d_ws;
  float* outp = (float*)d_out;
  float* H1   = ws + WS_H1;
  float* Wt   = ws + WS_WT;
  float* H2   = ws + WS_H2;
  float* WC1  = ws + WS_WC1;
  float* WC2  = ws + WS_WC2;
  float* WfcT = ws + WS_WFCT;

  hipLaunchKernelGGL(prep_w1,  dim3((IN1*G4 + 255)/256), dim3(256), 0, stream, Wih1, Whh1, WC1);
  hipLaunchKernelGGL(prep_w2,  dim3((IN2*G4 + 255)/256), dim3(256), 0, stream, Wih2, Whh2, WC2);
  hipLaunchKernelGGL(prep_wfc, dim3((FCIN*FCOUT + 255)/256), dim3(256), 0, stream, Wfc, WfcT);

  hipLaunchKernelGGL(pass1_kernel, dim3(BB), dim3(1024), 0, stream,
                     strokes, onehots, tmask, WC1, b1, Wwin, bwin, H1, Wt, outp);
  hipLaunchKernelGGL(pass2_kernel, dim3(BB), dim3(1024), 0, stream,
                     strokes, Wt, H1, WC2, b2, H2, outp);
  hipLaunchKernelGGL(fc_kernel, dim3(BB*TT/8), dim3(128), 0, stream,
                     H1, H2, WfcT, bfc, outp);
}

// Round 2
// 55534.430 us; speedup vs baseline: 3.6619x; 3.6619x over previous
//
#include <hip/hip_runtime.h>
#include <hip/hip_bf16.h>
#include <math.h>

#define HIDN 400
#define G4   1600
#define KK   10
#define UU   64
#define DD   60
#define TT   600
#define BB   64
#define FCIN 800
#define FCOUT 121

#define PBLK 200      // persistent blocks (1 per CU, LDS-forced)
#define NWB  64       // window blocks (one batch each)
#define THR  512      // threads per block (8 waves)
#define CB   8        // gate-columns per block per LSTM (2 hidden units)
#define NW8  8        // waves per block

// ---- d_out offsets (floats) ----
#define PI_OFF    0
#define MU_OFF    768000
#define SIG_OFF   2304000
#define RHO_OFF   3840000
#define EOS_OFF   4608000
#define WF_OFF    4646400
#define KAPPA_OFF 4650240
#define PHI_OFF   4650880
#define H0F_OFF   4654976
#define C0F_OFF   4680576
#define H1F_OFF   4706176
#define C1F_OFF   4731776

// ---- workspace offsets (floats) ----
#define WS_H1    0            // 15,360,000
#define WS_H2    15360000     // 15,360,000
#define WS_XU    30720000     // 2*864*64 = 110,592
#define WS_XST   30830592     // 600*3*64 = 115,200
#define WS_WALL1 30945792     // 200*463*8 = 740,800
#define WS_WALL2 31686592     // 200*863*8 = 1,380,800
#define WS_WFCT  33067392     // 96,800
#define WS_CNT   33164192     // 1216 ints
// total ~33.17M floats = 133 MB (prev round used 141MB OK)

#define XUSTRIDE 55296        // 864*64

__device__ __forceinline__ float sigm(float x){ return 1.0f/(1.0f + expf(-x)); }

// ---------- prep: zero XU/counters, init w rows of buf0, strokes transpose ----------
__global__ void prep_init(const float* __restrict__ onehots, const float* __restrict__ strokes,
                          float* __restrict__ XU, float* __restrict__ XST, int* __restrict__ cnts){
  int idx = blockIdx.x*blockDim.x + threadIdx.x;
  if (idx < 2*XUSTRIDE){
    int buf = idx / XUSTRIDE, rem = idx % XUSTRIDE, row = rem/64, b = rem%64;
    float v = 0.f;
    if (buf==0 && row>=800 && row<860) v = onehots[b*(UU*DD) + (row-800)];  // onehots[b,0,d]
    XU[idx] = v;
  }
  if (idx < TT*3*64){
    int t = idx/192, rem = idx%192, comp = rem/64, b = rem%64;
    XST[idx] = strokes[(b*TT + t)*3 + comp];
  }
  if (idx < 1216) cnts[idx] = 0;
}

// ---------- prep: reorder weights, thread per SOURCE element (coalesced reads) ----------
// block p owns hidden units {2p, 2p+1}; col c = 2*q + (j&1), gates q: 0=i,1=f,2=g,3=o
// WALL1 rows r: [0,400)=h1, [400,460)=w, [460,463)=x
// WALL2 rows r: [0,400)=h1, [400,800)=h2, [800,860)=w, [860,863)=x
__global__ void prep_wall(const float* __restrict__ Wih1, const float* __restrict__ Whh1,
                          const float* __restrict__ Wih2, const float* __restrict__ Whh2,
                          float* __restrict__ WALL1, float* __restrict__ WALL2){
  int idx = blockIdx.x*blockDim.x + threadIdx.x;
  if (idx < 640000){                       // W_hh1 (1600,400)
    int g = idx/400, k = idx%400;
    int q = g/400, j = g%400, p = j>>1, c = 2*q + (j&1);
    WALL1[(p*463 + k)*CB + c] = Whh1[idx];
  } else if (idx < 740800){                // W_ih1 (1600,63): cols 0-2 x, 3-62 w
    int s = idx - 640000;
    int g = s/63, col = s%63;
    int q = g/400, j = g%400, p = j>>1, c = 2*q + (j&1);
    int r = (col < 3) ? (460 + col) : (400 + col - 3);
    WALL1[(p*463 + r)*CB + c] = Wih1[s];
  } else if (idx < 1380800){               // W_hh2 (1600,400)
    int s = idx - 740800;
    int g = s/400, k = s%400;
    int q = g/400, j = g%400, p = j>>1, c = 2*q + (j&1);
    WALL2[(p*863 + 400 + k)*CB + c] = Whh2[s];
  } else if (idx < 2121600){               // W_ih2 (1600,463): 0-2 x, 3-62 w, 63-462 h1
    int s = idx - 1380800;
    int g = s/463, col = s%463;
    int q = g/400, j = g%400, p = j>>1, c = 2*q + (j&1);
    int r = (col<3) ? (860+col) : (col<63 ? (800+col-3) : (col-63));
    WALL2[(p*863 + r)*CB + c] = Wih2[s];
  }
}

__global__ void prep_wfc(const float* __restrict__ Wfc, float* __restrict__ WfcT){
  int idx = blockIdx.x*blockDim.x + threadIdx.x;
  if (idx >= FCIN*FCOUT) return;
  int k = idx / FCOUT, j = idx - k*FCOUT;
  WfcT[idx] = Wfc[j*FCIN + k];
}

// ---------- GEMV segment: x rows advance by 64 floats; weights LDS ----------
__device__ __forceinline__ void gemv_seg(const float* __restrict__ x,
                                         const float* __restrict__ w,
                                         int n, int bg4, int cg2, float acc[8]){
  #pragma unroll 4
  for (int k=0;k<n;++k){
    const float4 xv = *(const float4*)(x + k*64 + bg4);
    const float2 wv = *(const float2*)(w + k*CB + cg2);
    acc[0] = fmaf(wv.x, xv.x, acc[0]);
    acc[1] = fmaf(wv.x, xv.y, acc[1]);
    acc[2] = fmaf(wv.x, xv.z, acc[2]);
    acc[3] = fmaf(wv.x, xv.w, acc[3]);
    acc[4] = fmaf(wv.y, xv.x, acc[4]);
    acc[5] = fmaf(wv.y, xv.y, acc[5]);
    acc[6] = fmaf(wv.y, xv.z, acc[6]);
    acc[7] = fmaf(wv.y, xv.w, acc[7]);
  }
}

// ---------- persistent recurrent kernel ----------
__global__ __launch_bounds__(THR) void recurrent_kernel(
    const float* __restrict__ Wwin, const float* __restrict__ bwin,
    const float* __restrict__ b1g,  const float* __restrict__ b2g,
    const float* __restrict__ tmask,const float* __restrict__ onehots,
    const float* __restrict__ WALL1,const float* __restrict__ WALL2,
    float* __restrict__ XU,         const float* __restrict__ XST,
    float* __restrict__ H1ws,       float* __restrict__ H2ws,
    int* __restrict__ cnts,         float* __restrict__ outp)
{
  const int p    = blockIdx.x;
  const int tid  = threadIdx.x;
  const int wave = tid >> 6, lane = tid & 63;
  const int bg4  = (lane & 15) * 4;   // batches bg4..bg4+3
  const int cg2  = (lane >> 4) * 2;   // cols  cg2..cg2+1 (block-local)

  __shared__ float WL1[463*CB];
  __shared__ float WL2[863*CB];
  __shared__ float part[NW8][CB][64];
  __shared__ float gred[CB][64];
  __shared__ float cs1[2][64], cs2[2][64];
  __shared__ float bs1[CB], bs2[CB];
  // window-block-only area
  __shared__ float WwinS[30*400];
  __shared__ float onehS[UU*DD];
  __shared__ float tmaskS[UU];
  __shared__ float hbuf[HIDN];
  __shared__ float pw[30];
  __shared__ float kap[KK];
  __shared__ float phiS[UU];

  for (int idx = tid; idx < 463*CB; idx += THR) WL1[idx] = WALL1[p*463*CB + idx];
  for (int idx = tid; idx < 863*CB; idx += THR) WL2[idx] = WALL2[p*863*CB + idx];
  if (tid < CB){ int q = tid>>1, u = tid&1; int j = 2*p+u;
    bs1[tid] = b1g[q*HIDN + j]; bs2[tid] = b2g[q*HIDN + j]; }
  if (tid < 128){ cs1[tid>>6][tid&63] = 0.f; cs2[tid>>6][tid&63] = 0.f; }
  if (p < NWB){
    for (int idx = tid; idx < 30*400; idx += THR) WwinS[idx] = Wwin[idx];
    for (int idx = tid; idx < UU*DD;  idx += THR) onehS[idx] = onehots[p*(UU*DD) + idx];
    if (tid < UU) tmaskS[tid] = tmask[p*UU + tid];
    if (tid < KK) kap[tid] = 0.f;
  }
  __syncthreads();

  int* cnt_h1 = cnts;
  int* cntM   = cnts + 608;

  for (int i = 0; i <= TT; ++i){
    float* XUcur = XU + (i & 1) * XUSTRIDE;
    float* XUnxt = XU + ((i + 1) & 1) * XUSTRIDE;

    if (i < TT){
      // ---- GEMV1 (step t=i): rows [0,400)=h1, [400,460)=w(+400 in XU), [460,463)=x
      float acc[8] = {0,0,0,0,0,0,0,0};
      int k0 = wave*58, k1 = min(k0 + 58, 463);
      { int ka = k0, kb = min(k1, 400);
        if (kb > ka) gemv_seg(XUcur + ka*64, WL1 + ka*CB, kb-ka, bg4, cg2, acc); }
      { int ka = max(k0,400), kb = min(k1, 460);
        if (kb > ka) gemv_seg(XUcur + (ka+400)*64, WL1 + ka*CB, kb-ka, bg4, cg2, acc); }
      { int ka = max(k0,460), kb = k1;
        if (kb > ka) gemv_seg(XST + i*192 + (ka-460)*64, WL1 + ka*CB, kb-ka, bg4, cg2, acc); }
      *(float4*)&part[wave][cg2  ][bg4] = make_float4(acc[0],acc[1],acc[2],acc[3]);
      *(float4*)&part[wave][cg2+1][bg4] = make_float4(acc[4],acc[5],acc[6],acc[7]);
      __syncthreads();
      { int c = tid>>6, b = tid&63; float s = 0.f;
        #pragma unroll
        for (int w8=0; w8<NW8; ++w8) s += part[w8][c][b];
        gred[c][b] = s; }
      __syncthreads();
      if (tid < 128){
        int u = tid>>6, b = tid&63, j = 2*p + u;
        float gi = gred[0+u][b] + bs1[0+u];
        float gf = gred[2+u][b] + bs1[2+u];
        float gg = gred[4+u][b] + bs1[4+u];
        float go = gred[6+u][b] + bs1[6+u];
        float c_ = sigm(gf)*cs1[u][b] + sigm(gi)*tanhf(gg);
        float h_ = sigm(go)*tanhf(c_);
        cs1[u][b] = c_;
        XUnxt[j*64 + b] = h_;
        H1ws[((size_t)(b*TT + i))*HIDN + j] = h_;
        if (i == TT-1){ outp[H0F_OFF + b*HIDN + j] = h_; outp[C0F_OFF + b*HIDN + j] = c_; }
      }
      __threadfence();
      __syncthreads();
      if (tid == 0) atomicAdd(&cnt_h1[i], 1);
    }

    if (i >= 1){
      // ---- GEMV2 (step t2=i-1): rows [0,860) map directly to XU rows, [860,863)=x
      const int t2 = i - 1;
      float acc[8] = {0,0,0,0,0,0,0,0};
      int k0 = wave*108, k1 = min(k0 + 108, 863);
      { int ka = k0, kb = min(k1, 860);
        if (kb > ka) gemv_seg(XUcur + ka*64, WL2 + ka*CB, kb-ka, bg4, cg2, acc); }
      { int ka = max(k0,860), kb = k1;
        if (kb > ka) gemv_seg(XST + t2*192 + (ka-860)*64, WL2 + ka*CB, kb-ka, bg4, cg2, acc); }
      __syncthreads();   // part may still be read by none; safe ordering before overwrite
      *(float4*)&part[wave][cg2  ][bg4] = make_float4(acc[0],acc[1],acc[2],acc[3]);
      *(float4*)&part[wave][cg2+1][bg4] = make_float4(acc[4],acc[5],acc[6],acc[7]);
      __syncthreads();
      { int c = tid>>6, b = tid&63; float s = 0.f;
        #pragma unroll
        for (int w8=0; w8<NW8; ++w8) s += part[w8][c][b];
        gred[c][b] = s; }
      __syncthreads();
      if (tid < 128){
        int u = tid>>6, b = tid&63, j = 2*p + u;
        float gi = gred[0+u][b] + bs2[0+u];
        float gf = gred[2+u][b] + bs2[2+u];
        float gg = gred[4+u][b] + bs2[4+u];
        float go = gred[6+u][b] + bs2[6+u];
        float c_ = sigm(gf)*cs2[u][b] + sigm(gi)*tanhf(gg);
        float h_ = sigm(go)*tanhf(c_);
        cs2[u][b] = c_;
        XUnxt[(400+j)*64 + b] = h_;
        H2ws[((size_t)(b*TT + t2))*HIDN + j] = h_;
        if (i == TT){ outp[H1F_OFF + b*HIDN + j] = h_; outp[C1F_OFF + b*HIDN + j] = c_; }
      }
    }

    // ---- window/attention for step t=i (blocks 0..63, one batch each)
    if (p < NWB && i < TT){
      const int b = p;
      if (tid == 0){
        while (__hip_atomic_load(&cnt_h1[i], __ATOMIC_ACQUIRE, __HIP_MEMORY_SCOPE_AGENT) < PBLK)
          __builtin_amdgcn_s_sleep(2);
      }
      __syncthreads();
      for (int k = tid; k < HIDN; k += THR) hbuf[k] = XUnxt[k*64 + b];
      __syncthreads();
      if (tid < 480){
        int j = tid >> 4, l = tid & 15;
        float s = 0.f;
        for (int k = l; k < HIDN; k += 16) s = fmaf(hbuf[k], WwinS[j*HIDN + k], s);
        s += __shfl_down(s, 8, 16);
        s += __shfl_down(s, 4, 16);
        s += __shfl_down(s, 2, 16);
        s += __shfl_down(s, 1, 16);
        if (l == 0) pw[j] = expf(s + bwin[j]);
      }
      __syncthreads();
      if (tid < KK) kap[tid] += pw[20 + tid];
      __syncthreads();
      if (tid < UU){
        float u = (float)tid, s = 0.f;
        #pragma unroll
        for (int q = 0; q < KK; ++q){
          float d = kap[q] - u;
          s = fmaf(pw[q], expf(-pw[KK+q]*d*d), s);
        }
        s *= tmaskS[tid];
        phiS[tid] = s;
        if (i == TT-1) outp[PHI_OFF + b*UU + tid] = s;
      }
      __syncthreads();
      if (tid < DD){
        float s = 0.f;
        for (int u = 0; u < UU; ++u) s = fmaf(phiS[u], onehS[u*DD + tid], s);
        XUnxt[(800 + tid)*64 + b] = s;
        if (i == TT-1) outp[WF_OFF + b*DD + tid] = s;
      }
      if (tid < KK && i == TT-1) outp[KAPPA_OFF + b*KK + tid] = kap[tid];
    }

    // ---- main barrier (publish h1(i), h2(i-1), w(i))
    if (i < TT){
      __threadfence();
      __syncthreads();
      if (tid == 0){
        atomicAdd(&cntM[i], 1);
        while (__hip_atomic_load(&cntM[i], __ATOMIC_ACQUIRE, __HIP_MEMORY_SCOPE_AGENT) < PBLK)
          __builtin_amdgcn_s_sleep(2);
      }
      __syncthreads();
    }
  }
}

// ---------- Final FC + heads ----------
__global__ __launch_bounds__(128) void fc_kernel(
    const float* __restrict__ H1, const float* __restrict__ H2,
    const float* __restrict__ WfcT, const float* __restrict__ bfc,
    float* __restrict__ outp)
{
  const int tile = blockIdx.x;
  const int tid  = threadIdx.x;
  __shared__ float X[8][FCIN];
  __shared__ float PS[8][20];
  const size_t base = (size_t)tile * 8;

  for (int i = tid; i < 8*FCIN; i += 128){
    int pp = i / FCIN, k = i - pp*FCIN;
    size_t pos = base + pp;
    X[pp][k] = (k < HIDN) ? H1[pos*HIDN + k] : H2[pos*HIDN + (k - HIDN)];
  }
  __syncthreads();

  if (tid < FCOUT){
    float acc[8];
    float bj = bfc[tid];
    #pragma unroll
    for (int pp=0; pp<8; ++pp) acc[pp] = bj;
    for (int k=0; k<FCIN; ++k){
      float wv = WfcT[k*FCOUT + tid];
      #pragma unroll
      for (int pp=0; pp<8; ++pp) acc[pp] = fmaf(X[pp][k], wv, acc[pp]);
    }
    const int j = tid;
    for (int pp=0; pp<8; ++pp){
      size_t pos = base + pp;
      float v = acc[pp];
      if (j < 40)       outp[MU_OFF  + pos*40 + j]       = v;
      else if (j < 80)  outp[SIG_OFF + pos*40 + (j-40)]  = v;
      else if (j < 100) PS[pp][j-80] = v;
      else if (j < 120) outp[RHO_OFF + pos*20 + (j-100)] = tanhf(v);
      else              outp[EOS_OFF + pos]              = 1.0f/(1.0f + expf(v));
    }
  }
  __syncthreads();

  if (tid < 8){
    size_t pos = base + tid;
    float m = -1e30f;
    #pragma unroll
    for (int j=0;j<20;++j) m = fmaxf(m, PS[tid][j]);
    float e[20], s = 0.f;
    #pragma unroll
    for (int j=0;j<20;++j){ e[j] = expf(PS[tid][j]-m); s += e[j]; }
    float inv = 1.0f/s;
    #pragma unroll
    for (int j=0;j<20;++j) outp[PI_OFF + pos*20 + j] = e[j]*inv;
  }
}

extern "C" void kernel_launch(void* const* d_in, const int* in_sizes, int n_in,
                              void* d_out, int out_size, void* d_ws, size_t ws_size,
                              hipStream_t stream){
  (void)in_sizes; (void)n_in; (void)out_size; (void)ws_size;
  const float* strokes = (const float*)d_in[0];
  const float* onehots = (const float*)d_in[1];
  const float* tmask   = (const float*)d_in[2];
  const float* Wih1    = (const float*)d_in[3];
  const float* Whh1    = (const float*)d_in[4];
  const float* b1      = (const float*)d_in[5];
  const float* Wwin    = (const float*)d_in[6];
  const float* bwin    = (const float*)d_in[7];
  const float* Wih2    = (const float*)d_in[8];
  const float* Whh2    = (const float*)d_in[9];
  const float* b2      = (const float*)d_in[10];
  const float* Wfc     = (const float*)d_in[11];
  const float* bfc     = (const float*)d_in[12];

  float* ws   = (float*)d_ws;
  float* outp = (float*)d_out;
  float* H1   = ws + WS_H1;
  float* H2   = ws + WS_H2;
  float* XU   = ws + WS_XU;
  float* XST  = ws + WS_XST;
  float* WALL1= ws + WS_WALL1;
  float* WALL2= ws + WS_WALL2;
  float* WfcT = ws + WS_WFCT;
  int*   cnts = (int*)(ws + WS_CNT);

  hipLaunchKernelGGL(prep_init, dim3((TT*3*64 + 255)/256), dim3(256), 0, stream,
                     onehots, strokes, XU, XST, cnts);
  hipLaunchKernelGGL(prep_wall, dim3((2121600 + 255)/256), dim3(256), 0, stream,
                     Wih1, Whh1, Wih2, Whh2, WALL1, WALL2);
  hipLaunchKernelGGL(prep_wfc, dim3((FCIN*FCOUT + 255)/256), dim3(256), 0, stream,
                     Wfc, WfcT);

  hipLaunchKernelGGL(recurrent_kernel, dim3(PBLK), dim3(THR), 0, stream,
                     Wwin, bwin, b1, b2, tmask, onehots, WALL1, WALL2,
                     XU, XST, H1, H2, cnts, outp);

  hipLaunchKernelGGL(fc_kernel, dim3(BB*TT/8), dim3(128), 0, stream,
                     H1, H2, WfcT, bfc, outp);
}

// Round 3
// 31478.989 us; speedup vs baseline: 6.4603x; 1.7642x over previous
//
#include <hip/hip_runtime.h>
#include <hip/hip_bf16.h>
#include <math.h>

#define HIDN 400
#define KK   10
#define UU   64
#define DD   60
#define TT   600
#define BB   64
#define FCIN 800
#define FCOUT 121

#define PBLK 200      // persistent blocks (1 per CU, LDS-forced; 200 <= 256 CUs)
#define NWB  64       // window duty on blocks 0..63 (one batch each)
#define THR  512      // 8 waves
#define CB   8        // gate-columns per block per LSTM (2 hidden units)
#define NW8  8

#define SLOT1 25600   // 400*64  (one step of h1 or h2 history)
#define SLOTW 3840    // 60*64   (one step of w history)

// ---- d_out offsets (floats) ----
#define PI_OFF    0
#define MU_OFF    768000
#define SIG_OFF   2304000
#define RHO_OFF   3840000
#define EOS_OFF   4608000
#define WF_OFF    4646400
#define KAPPA_OFF 4650240
#define PHI_OFF   4650880
#define H0F_OFF   4654976
#define C0F_OFF   4680576
#define H1F_OFF   4706176
#define C1F_OFF   4731776

// ---- workspace offsets (floats) ----
#define WS_H1T   0                  // 601*25600 = 15,385,600  (slot -1 zeroed)
#define WS_H2T   15385600           // 601*25600 = 15,385,600  (slot -1 zeroed)
#define WS_WHT   30771200           // 601*3840  = 2,307,840   (slot -1 = onehots[:,0,:])
#define WS_XST   33079040           // 600*3*64  = 115,200
#define WS_WALL1 33194240           // 200*463*8 = 740,800
#define WS_WALL2 33935040           // 200*863*8 = 1,380,800
#define WS_WFCT  35315840           // 800*121   = 96,800
#define WS_CNT   35412640           // 1216 ints
// total = 35,413,856 floats = 141.7 MB

__device__ __forceinline__ float sigm(float x){ return 1.0f/(1.0f + expf(-x)); }

// write-through publish (lands at IF$, visible cross-XCD; no wbl2 needed)
__device__ __forceinline__ void st_agent(float* p, float v){
  __hip_atomic_store(p, v, __ATOMIC_RELAXED, __HIP_MEMORY_SCOPE_AGENT);
}
__device__ __forceinline__ int ld_cnt(const int* p){
  return __hip_atomic_load(p, __ATOMIC_RELAXED, __HIP_MEMORY_SCOPE_AGENT);
}

// ---------- prep ----------
__global__ void prep_init(const float* __restrict__ onehots, const float* __restrict__ strokes,
                          float* __restrict__ H1t, float* __restrict__ H2t,
                          float* __restrict__ Wh,  float* __restrict__ XST,
                          int* __restrict__ cnts){
  int idx = blockIdx.x*blockDim.x + threadIdx.x;
  if (idx < SLOT1){ H1t[idx] = 0.f; H2t[idx] = 0.f; }
  if (idx < SLOTW){
    int d = idx >> 6, b = idx & 63;
    Wh[idx] = onehots[b*(UU*DD) + d];            // onehots[b, u=0, d]
  }
  if (idx < TT*3*64){
    int t = idx/192, rem = idx%192, comp = rem/64, b = rem%64;
    XST[idx] = strokes[(b*TT + t)*3 + comp];
  }
  if (idx < 1216) cnts[idx] = 0;
}

// ---------- weight reorder (thread per SOURCE element) ----------
// block p owns hidden units {2p,2p+1}; col c = 2*q + (j&1), gates q: 0=i,1=f,2=g,3=o
// WALL1 rows: [0,400)=h1, [400,460)=w, [460,463)=x
// WALL2 rows: [0,400)=h1, [400,800)=h2, [800,860)=w, [860,863)=x
__global__ void prep_wall(const float* __restrict__ Wih1, const float* __restrict__ Whh1,
                          const float* __restrict__ Wih2, const float* __restrict__ Whh2,
                          float* __restrict__ WALL1, float* __restrict__ WALL2){
  int idx = blockIdx.x*blockDim.x + threadIdx.x;
  if (idx < 640000){                       // W_hh1 (1600,400)
    int g = idx/400, k = idx%400;
    int q = g/400, j = g%400, p = j>>1, c = 2*q + (j&1);
    WALL1[(p*463 + k)*CB + c] = Whh1[idx];
  } else if (idx < 740800){                // W_ih1 (1600,63)
    int s = idx - 640000;
    int g = s/63, col = s%63;
    int q = g/400, j = g%400, p = j>>1, c = 2*q + (j&1);
    int r = (col < 3) ? (460 + col) : (400 + col - 3);
    WALL1[(p*463 + r)*CB + c] = Wih1[s];
  } else if (idx < 1380800){               // W_hh2 (1600,400)
    int s = idx - 740800;
    int g = s/400, k = s%400;
    int q = g/400, j = g%400, p = j>>1, c = 2*q + (j&1);
    WALL2[(p*863 + 400 + k)*CB + c] = Whh2[s];
  } else if (idx < 2121600){               // W_ih2 (1600,463)
    int s = idx - 1380800;
    int g = s/463, col = s%463;
    int q = g/400, j = g%400, p = j>>1, c = 2*q + (j&1);
    int r = (col<3) ? (860+col) : (col<63 ? (800+col-3) : (col-63));
    WALL2[(p*863 + r)*CB + c] = Wih2[s];
  }
}

__global__ void prep_wfc(const float* __restrict__ Wfc, float* __restrict__ WfcT){
  int idx = blockIdx.x*blockDim.x + threadIdx.x;
  if (idx >= FCIN*FCOUT) return;
  int k = idx / FCOUT, j = idx - k*FCOUT;
  WfcT[idx] = Wfc[j*FCIN + k];
}

// ---------- GEMV segment ----------
__device__ __forceinline__ void gemv_seg(const float* __restrict__ x,
                                         const float* __restrict__ w,
                                         int n, int bg4, int cg2, float acc[8]){
  #pragma unroll 4
  for (int k=0;k<n;++k){
    const float4 xv = *(const float4*)(x + k*64 + bg4);
    const float2 wv = *(const float2*)(w + k*CB + cg2);
    acc[0] = fmaf(wv.x, xv.x, acc[0]);
    acc[1] = fmaf(wv.x, xv.y, acc[1]);
    acc[2] = fmaf(wv.x, xv.z, acc[2]);
    acc[3] = fmaf(wv.x, xv.w, acc[3]);
    acc[4] = fmaf(wv.y, xv.x, acc[4]);
    acc[5] = fmaf(wv.y, xv.y, acc[5]);
    acc[6] = fmaf(wv.y, xv.z, acc[6]);
    acc[7] = fmaf(wv.y, xv.w, acc[7]);
  }
}

// ---------- persistent recurrent kernel ----------
__global__ __launch_bounds__(THR) void recurrent_kernel(
    const float* __restrict__ Wwin, const float* __restrict__ bwin,
    const float* __restrict__ b1g,  const float* __restrict__ b2g,
    const float* __restrict__ tmask,const float* __restrict__ onehots,
    const float* __restrict__ WALL1,const float* __restrict__ WALL2,
    float* __restrict__ H1t,        float* __restrict__ H2t,
    float* __restrict__ Wh,         const float* __restrict__ XST,
    int* __restrict__ cnts,         float* __restrict__ outp)
{
  const int p    = blockIdx.x;
  const int tid  = threadIdx.x;
  const int wave = tid >> 6, lane = tid & 63;
  const int bg4  = (lane & 15) * 4;
  const int cg2  = (lane >> 4) * 2;

  __shared__ float WL1[463*CB];
  __shared__ float WL2[863*CB];
  __shared__ float part[NW8][CB][64];
  __shared__ float gred[CB][64];
  __shared__ float cs1[2][64], cs2[2][64];
  __shared__ float bs1[CB], bs2[CB];
  __shared__ float WwinS[30*400];
  __shared__ float onehS[UU*DD];
  __shared__ float tmaskS[UU];
  __shared__ float hbuf[HIDN];
  __shared__ float pw[30];
  __shared__ float kap[KK];
  __shared__ float phiS[UU];

  for (int idx = tid; idx < 463*CB; idx += THR) WL1[idx] = WALL1[p*463*CB + idx];
  for (int idx = tid; idx < 863*CB; idx += THR) WL2[idx] = WALL2[p*863*CB + idx];
  if (tid < CB){ int q = tid>>1, u = tid&1; int j = 2*p+u;
    bs1[tid] = b1g[q*HIDN + j]; bs2[tid] = b2g[q*HIDN + j]; }
  if (tid < 128){ cs1[tid>>6][tid&63] = 0.f; cs2[tid>>6][tid&63] = 0.f; }
  if (p < NWB){
    for (int idx = tid; idx < 30*400; idx += THR) WwinS[idx] = Wwin[idx];
    for (int idx = tid; idx < UU*DD;  idx += THR) onehS[idx] = onehots[p*(UU*DD) + idx];
    if (tid < UU) tmaskS[tid] = tmask[p*UU + tid];
    if (tid < KK) kap[tid] = 0.f;
  }
  __syncthreads();

  int* cnt_h1 = cnts;
  int* cntM   = cnts + 608;

  for (int i = 0; i <= TT; ++i){
    if (i < TT){
      // ---- GEMV1 step t=i: h1(i-1) @ rows[0,400), w(i-1) @ [400,460), x(i) @ [460,463)
      const float* __restrict__ H1prev = H1t + (size_t)i*SLOT1;   // slot i-1
      const float* __restrict__ Whprev = Wh  + (size_t)i*SLOTW;   // slot i-1
      float acc[8] = {0,0,0,0,0,0,0,0};
      int k0 = wave*58, k1 = min(k0 + 58, 463);
      { int ka = k0, kb = min(k1, 400);
        if (kb > ka) gemv_seg(H1prev + ka*64, WL1 + ka*CB, kb-ka, bg4, cg2, acc); }
      { int ka = max(k0,400), kb = min(k1, 460);
        if (kb > ka) gemv_seg(Whprev + (ka-400)*64, WL1 + ka*CB, kb-ka, bg4, cg2, acc); }
      { int ka = max(k0,460), kb = k1;
        if (kb > ka) gemv_seg(XST + i*192 + (ka-460)*64, WL1 + ka*CB, kb-ka, bg4, cg2, acc); }
      *(float4*)&part[wave][cg2  ][bg4] = make_float4(acc[0],acc[1],acc[2],acc[3]);
      *(float4*)&part[wave][cg2+1][bg4] = make_float4(acc[4],acc[5],acc[6],acc[7]);
      __syncthreads();
      { int c = tid>>6, b = tid&63; float s = 0.f;
        #pragma unroll
        for (int w8=0; w8<NW8; ++w8) s += part[w8][c][b];
        gred[c][b] = s; }
      __syncthreads();
      if (tid < 128){
        int u = tid>>6, b = tid&63, j = 2*p + u;
        float gi = gred[0+u][b] + bs1[0+u];
        float gf = gred[2+u][b] + bs1[2+u];
        float gg = gred[4+u][b] + bs1[4+u];
        float go = gred[6+u][b] + bs1[6+u];
        float c_ = sigm(gf)*cs1[u][b] + sigm(gi)*tanhf(gg);
        float h_ = sigm(go)*tanhf(c_);
        cs1[u][b] = c_;
        st_agent(&H1t[(size_t)(i+1)*SLOT1 + j*64 + b], h_);   // publish h1(i)
        if (i == TT-1){ outp[H0F_OFF + b*HIDN + j] = h_; outp[C0F_OFF + b*HIDN + j] = c_; }
      }
      __syncthreads();                       // drains vmcnt (publishes complete)
      if (tid == 0)
        __hip_atomic_fetch_add(&cnt_h1[i], 1, __ATOMIC_RELAXED, __HIP_MEMORY_SCOPE_AGENT);
    }

    if (i >= 1){
      // ---- GEMV2 step t2=i-1: h1(i-1), h2(i-2), w(i-1), x(i-1)
      const int t2 = i - 1;
      const float* __restrict__ H1cur = H1t + (size_t)i*SLOT1;       // h1(i-1)
      const float* __restrict__ H2pp  = H2t + (size_t)(i-1)*SLOT1;   // h2(i-2)
      const float* __restrict__ Whcur = Wh  + (size_t)i*SLOTW;       // w(i-1)
      float acc[8] = {0,0,0,0,0,0,0,0};
      int k0 = wave*108, k1 = min(k0 + 108, 863);
      { int ka = k0, kb = min(k1, 400);
        if (kb > ka) gemv_seg(H1cur + ka*64, WL2 + ka*CB, kb-ka, bg4, cg2, acc); }
      { int ka = max(k0,400), kb = min(k1, 800);
        if (kb > ka) gemv_seg(H2pp + (ka-400)*64, WL2 + ka*CB, kb-ka, bg4, cg2, acc); }
      { int ka = max(k0,800), kb = min(k1, 860);
        if (kb > ka) gemv_seg(Whcur + (ka-800)*64, WL2 + ka*CB, kb-ka, bg4, cg2, acc); }
      { int ka = max(k0,860), kb = k1;
        if (kb > ka) gemv_seg(XST + t2*192 + (ka-860)*64, WL2 + ka*CB, kb-ka, bg4, cg2, acc); }
      *(float4*)&part[wave][cg2  ][bg4] = make_float4(acc[0],acc[1],acc[2],acc[3]);
      *(float4*)&part[wave][cg2+1][bg4] = make_float4(acc[4],acc[5],acc[6],acc[7]);
      __syncthreads();
      { int c = tid>>6, b = tid&63; float s = 0.f;
        #pragma unroll
        for (int w8=0; w8<NW8; ++w8) s += part[w8][c][b];
        gred[c][b] = s; }
      __syncthreads();
      if (tid < 128){
        int u = tid>>6, b = tid&63, j = 2*p + u;
        float gi = gred[0+u][b] + bs2[0+u];
        float gf = gred[2+u][b] + bs2[2+u];
        float gg = gred[4+u][b] + bs2[4+u];
        float go = gred[6+u][b] + bs2[6+u];
        float c_ = sigm(gf)*cs2[u][b] + sigm(gi)*tanhf(gg);
        float h_ = sigm(go)*tanhf(c_);
        cs2[u][b] = c_;
        st_agent(&H2t[(size_t)i*SLOT1 + j*64 + b], h_);       // publish h2(i-1)
        if (i == TT){ outp[H1F_OFF + b*HIDN + j] = h_; outp[C1F_OFF + b*HIDN + j] = c_; }
      }
    }

    // ---- window for step t=i (blocks 0..63)
    if (p < NWB && i < TT){
      const int b = p;
      if (tid == 0){
        while (ld_cnt(&cnt_h1[i]) < PBLK) __builtin_amdgcn_s_sleep(1);
        __builtin_amdgcn_fence(__ATOMIC_ACQUIRE, "agent");
      }
      __syncthreads();
      const float* __restrict__ H1now = H1t + (size_t)(i+1)*SLOT1;
      for (int k = tid; k < HIDN; k += THR) hbuf[k] = H1now[k*64 + b];
      __syncthreads();
      if (tid < 480){
        int j = tid >> 4, l = tid & 15;
        float s = 0.f;
        for (int k = l; k < HIDN; k += 16) s = fmaf(hbuf[k], WwinS[j*HIDN + k], s);
        s += __shfl_down(s, 8, 16);
        s += __shfl_down(s, 4, 16);
        s += __shfl_down(s, 2, 16);
        s += __shfl_down(s, 1, 16);
        if (l == 0) pw[j] = expf(s + bwin[j]);
      }
      __syncthreads();
      if (tid < KK) kap[tid] += pw[20 + tid];
      __syncthreads();
      if (tid < UU){
        float u = (float)tid, s = 0.f;
        #pragma unroll
        for (int q = 0; q < KK; ++q){
          float d = kap[q] - u;
          s = fmaf(pw[q], expf(-pw[KK+q]*d*d), s);
        }
        s *= tmaskS[tid];
        phiS[tid] = s;
        if (i == TT-1) outp[PHI_OFF + b*UU + tid] = s;
      }
      __syncthreads();
      if (tid < DD){
        float s = 0.f;
        for (int u = 0; u < UU; ++u) s = fmaf(phiS[u], onehS[u*DD + tid], s);
        st_agent(&Wh[(size_t)(i+1)*SLOTW + tid*64 + b], s);   // publish w(i)
        if (i == TT-1) outp[WF_OFF + b*DD + tid] = s;
      }
      if (tid < KK && i == TT-1) outp[KAPPA_OFF + b*KK + tid] = kap[tid];
    }

    // ---- main barrier: h1(i), h2(i-1), w(i) all published
    if (i < TT){
      __syncthreads();
      if (tid == 0){
        __hip_atomic_fetch_add(&cntM[i], 1, __ATOMIC_RELAXED, __HIP_MEMORY_SCOPE_AGENT);
        while (ld_cnt(&cntM[i]) < PBLK) __builtin_amdgcn_s_sleep(1);
        __builtin_amdgcn_fence(__ATOMIC_ACQUIRE, "agent");
      }
      __syncthreads();
    }
  }
}

// ---------- FC + heads: one block per timestep, coalesced reads of history ----------
__global__ __launch_bounds__(128) void fc2_kernel(
    const float* __restrict__ H1t, const float* __restrict__ H2t,
    const float* __restrict__ WfcT, const float* __restrict__ bfc,
    float* __restrict__ outp)
{
  const int t   = blockIdx.x;
  const int tid = threadIdx.x;
  __shared__ float Xs[8][64];
  __shared__ float OUT[FCOUT][65];
  float acc[64];
  #pragma unroll
  for (int b=0;b<64;++b) acc[b]=0.f;
  const float* __restrict__ base1 = H1t + (size_t)(t+1)*SLOT1;
  const float* __restrict__ base2 = H2t + (size_t)(t+1)*SLOT1;

  for (int kb=0; kb<100; ++kb){
    __syncthreads();
    #pragma unroll
    for (int e=0;e<4;++e){
      int idx = e*128 + tid;
      int row = idx>>6, b = idx&63;
      int k = kb*8 + row;
      Xs[row][b] = (k<400) ? base1[k*64+b] : base2[(k-400)*64+b];
    }
    __syncthreads();
    if (tid < FCOUT){
      #pragma unroll
      for (int kk=0;kk<8;++kk){
        float wv = WfcT[(kb*8+kk)*FCOUT + tid];
        #pragma unroll
        for (int b4=0;b4<16;++b4){
          float4 xv = *(const float4*)&Xs[kk][b4*4];
          acc[b4*4+0] = fmaf(wv, xv.x, acc[b4*4+0]);
          acc[b4*4+1] = fmaf(wv, xv.y, acc[b4*4+1]);
          acc[b4*4+2] = fmaf(wv, xv.z, acc[b4*4+2]);
          acc[b4*4+3] = fmaf(wv, xv.w, acc[b4*4+3]);
        }
      }
    }
  }
  if (tid < FCOUT){
    float bj = bfc[tid];
    #pragma unroll
    for (int b=0;b<64;++b) OUT[tid][b] = acc[b] + bj;
  }
  __syncthreads();
  if (tid < 64){
    const int b = tid;
    const size_t pos = (size_t)b*TT + t;
    for (int j=0;j<40;++j) outp[MU_OFF  + pos*40 + j] = OUT[j][b];
    for (int j=0;j<40;++j) outp[SIG_OFF + pos*40 + j] = OUT[40+j][b];
    float m = -1e30f;
    for (int q=0;q<20;++q) m = fmaxf(m, OUT[80+q][b]);
    float e[20], s=0.f;
    for (int q=0;q<20;++q){ e[q]=expf(OUT[80+q][b]-m); s+=e[q]; }
    float inv = 1.f/s;
    for (int q=0;q<20;++q) outp[PI_OFF  + pos*20 + q] = e[q]*inv;
    for (int q=0;q<20;++q) outp[RHO_OFF + pos*20 + q] = tanhf(OUT[100+q][b]);
    outp[EOS_OFF + pos] = 1.0f/(1.0f + expf(OUT[120][b]));
  }
}

extern "C" void kernel_launch(void* const* d_in, const int* in_sizes, int n_in,
                              void* d_out, int out_size, void* d_ws, size_t ws_size,
                              hipStream_t stream){
  (void)in_sizes; (void)n_in; (void)out_size; (void)ws_size;
  const float* strokes = (const float*)d_in[0];
  const float* onehots = (const float*)d_in[1];
  const float* tmask   = (const float*)d_in[2];
  const float* Wih1    = (const float*)d_in[3];
  const float* Whh1    = (const float*)d_in[4];
  const float* b1      = (const float*)d_in[5];
  const float* Wwin    = (const float*)d_in[6];
  const float* bwin    = (const float*)d_in[7];
  const float* Wih2    = (const float*)d_in[8];
  const float* Whh2    = (const float*)d_in[9];
  const float* b2      = (const float*)d_in[10];
  const float* Wfc     = (const float*)d_in[11];
  const float* bfc     = (const float*)d_in[12];

  float* ws    = (float*)d_ws;
  float* outp  = (float*)d_out;
  float* H1t   = ws + WS_H1T;
  float* H2t   = ws + WS_H2T;
  float* Wh    = ws + WS_WHT;
  float* XST   = ws + WS_XST;
  float* WALL1 = ws + WS_WALL1;
  float* WALL2 = ws + WS_WALL2;
  float* WfcT  = ws + WS_WFCT;
  int*   cnts  = (int*)(ws + WS_CNT);

  hipLaunchKernelGGL(prep_init, dim3((TT*3*64 + 255)/256), dim3(256), 0, stream,
                     onehots, strokes, H1t, H2t, Wh, XST, cnts);
  hipLaunchKernelGGL(prep_wall, dim3((2121600 + 255)/256), dim3(256), 0, stream,
                     Wih1, Whh1, Wih2, Whh2, WALL1, WALL2);
  hipLaunchKernelGGL(prep_wfc, dim3((FCIN*FCOUT + 255)/256), dim3(256), 0, stream,
                     Wfc, WfcT);

  hipLaunchKernelGGL(recurrent_kernel, dim3(PBLK), dim3(THR), 0, stream,
                     Wwin, bwin, b1, b2, tmask, onehots, WALL1, WALL2,
                     H1t, H2t, Wh, XST, cnts, outp);

  hipLaunchKernelGGL(fc2_kernel, dim3(TT), dim3(128), 0, stream,
                     H1t, H2t, WfcT, bfc, outp);
}

// Round 5
// 20843.483 us; speedup vs baseline: 9.7567x; 1.5103x over previous
//
#include <hip/hip_runtime.h>
#include <hip/hip_bf16.h>
#include <math.h>

#define HIDN 400
#define KK   10
#define UU   64
#define DD   60
#define TT   600
#define BB   64
#define FCIN 800
#define FCOUT 121

#define PBLK 200      // persistent blocks (1 per CU via LDS; 200 <= 256 CUs)
#define NWB  64       // window duty on blocks 0..63 (one batch each)
#define THR  1024     // 16 waves
#define NWAVE 16
#define CB   8        // gate-columns per block per LSTM (2 hidden units)
#define MA_BLK 64     // barrier-A master (h1-ready)
#define MM_BLK 65     // barrier-M master (step-done)

#define SLOT1 25600   // 400*64
#define SLOTW 3840    // 60*64

// ---- d_out offsets (floats) ----
#define PI_OFF    0
#define MU_OFF    768000
#define SIG_OFF   2304000
#define RHO_OFF   3840000
#define EOS_OFF   4608000
#define WF_OFF    4646400
#define KAPPA_OFF 4650240
#define PHI_OFF   4650880
#define H0F_OFF   4654976
#define C0F_OFF   4680576
#define H1F_OFF   4706176
#define C1F_OFF   4731776

// ---- workspace offsets (floats) ----
#define WS_H1T   0                  // 601*25600
#define WS_H2T   15385600           // 601*25600
#define WS_WHT   30771200           // 601*3840
#define WS_XST   33079040           // 600*3*64
#define WS_WALL1 33194240           // 200*463*8
#define WS_WALL2 33935040           // 200*863*8
#define WS_WFCT  35315840           // 800*121
#define WS_CNT   35412640           // 19456 ints (see layout below)
// total = 35,432,096 floats = 141.73 MB

// ---- cnt region layout (ints): line-padded (16 ints = 64B per word) ----
#define CNTA(i)  ((i)*16)           // arrivals, barrier A, per step
#define CNTM(i)  (9600 + (i)*16)    // arrivals, barrier M, per step
#define RELA(g)  (19200 + (g)*16)   // release words barrier A, 8 groups
#define RELM(g)  (19328 + (g)*16)   // release words barrier M, 8 groups
#define CNT_INTS 19456

__device__ __forceinline__ float sigm(float x){ return 1.0f/(1.0f + expf(-x)); }

__device__ __forceinline__ void st_agent(float* p, float v){
  __hip_atomic_store(p, v, __ATOMIC_RELAXED, __HIP_MEMORY_SCOPE_AGENT);
}
__device__ __forceinline__ void st_agent_i(int* p, int v){
  __hip_atomic_store(p, v, __ATOMIC_RELAXED, __HIP_MEMORY_SCOPE_AGENT);
}
__device__ __forceinline__ int ld_agent_i(const int* p){
  return __hip_atomic_load(p, __ATOMIC_RELAXED, __HIP_MEMORY_SCOPE_AGENT);
}
template<int SLP>
__device__ __forceinline__ void wait_ge(const int* w, int tgt){
  if (ld_agent_i(w) >= tgt) return;
  do { __builtin_amdgcn_s_sleep(SLP); } while (ld_agent_i(w) < tgt);
}

// ---------- prep ----------
__global__ void prep_init(const float* __restrict__ onehots, const float* __restrict__ strokes,
                          float* __restrict__ H1t, float* __restrict__ H2t,
                          float* __restrict__ Wh,  float* __restrict__ XST,
                          int* __restrict__ cnts){
  int idx = blockIdx.x*blockDim.x + threadIdx.x;
  if (idx < SLOT1){ H1t[idx] = 0.f; H2t[idx] = 0.f; }
  if (idx < SLOTW){
    int d = idx >> 6, b = idx & 63;
    Wh[idx] = onehots[b*(UU*DD) + d];            // onehots[b, u=0, d]
  }
  if (idx < TT*3*64){
    int t = idx/192, rem = idx%192, comp = rem/64, b = rem%64;
    XST[idx] = strokes[(b*TT + t)*3 + comp];
  }
  if (idx < CNT_INTS) cnts[idx] = 0;
}

// ---------- weight reorder ----------
// block p owns hidden units {2p,2p+1}; col c = 2*q + (j&1), gates q: 0=i,1=f,2=g,3=o
// WALL1 rows: [0,400)=h1, [400,460)=w, [460,463)=x
// WALL2 rows: [0,400)=h1, [400,800)=h2, [800,860)=w, [860,863)=x
__global__ void prep_wall(const float* __restrict__ Wih1, const float* __restrict__ Whh1,
                          const float* __restrict__ Wih2, const float* __restrict__ Whh2,
                          float* __restrict__ WALL1, float* __restrict__ WALL2){
  int idx = blockIdx.x*blockDim.x + threadIdx.x;
  if (idx < 640000){                       // W_hh1 (1600,400)
    int g = idx/400, k = idx%400;
    int q = g/400, j = g%400, p = j>>1, c = 2*q + (j&1);
    WALL1[(p*463 + k)*CB + c] = Whh1[idx];
  } else if (idx < 740800){                // W_ih1 (1600,63)
    int s = idx - 640000;
    int g = s/63, col = s%63;
    int q = g/400, j = g%400, p = j>>1, c = 2*q + (j&1);
    int r = (col < 3) ? (460 + col) : (400 + col - 3);
    WALL1[(p*463 + r)*CB + c] = Wih1[s];
  } else if (idx < 1380800){               // W_hh2 (1600,400)
    int s = idx - 740800;
    int g = s/400, k = s%400;
    int q = g/400, j = g%400, p = j>>1, c = 2*q + (j&1);
    WALL2[(p*863 + 400 + k)*CB + c] = Whh2[s];
  } else if (idx < 2121600){               // W_ih2 (1600,463)
    int s = idx - 1380800;
    int g = s/463, col = s%463;
    int q = g/400, j = g%400, p = j>>1, c = 2*q + (j&1);
    int r = (col<3) ? (860+col) : (col<63 ? (800+col-3) : (col-63));
    WALL2[(p*863 + r)*CB + c] = Wih2[s];
  }
}

__global__ void prep_wfc(const float* __restrict__ Wfc, float* __restrict__ WfcT){
  int idx = blockIdx.x*blockDim.x + threadIdx.x;
  if (idx >= FCIN*FCOUT) return;
  int k = idx / FCOUT, j = idx - k*FCOUT;
  WfcT[idx] = Wfc[j*FCIN + k];
}

// ---------- GEMV segment ----------
__device__ __forceinline__ void gemv_seg(const float* __restrict__ x,
                                         const float* __restrict__ w,
                                         int n, int bg4, int cg2, float acc[8]){
  #pragma unroll 4
  for (int k=0;k<n;++k){
    const float4 xv = *(const float4*)(x + k*64 + bg4);
    const float2 wv = *(const float2*)(w + k*CB + cg2);
    acc[0] = fmaf(wv.x, xv.x, acc[0]);
    acc[1] = fmaf(wv.x, xv.y, acc[1]);
    acc[2] = fmaf(wv.x, xv.z, acc[2]);
    acc[3] = fmaf(wv.x, xv.w, acc[3]);
    acc[4] = fmaf(wv.y, xv.x, acc[4]);
    acc[5] = fmaf(wv.y, xv.y, acc[5]);
    acc[6] = fmaf(wv.y, xv.z, acc[6]);
    acc[7] = fmaf(wv.y, xv.w, acc[7]);
  }
}

// ---------- persistent recurrent kernel ----------
__global__ __launch_bounds__(THR) void recurrent_kernel(
    const float* __restrict__ Wwin, const float* __restrict__ bwin,
    const float* __restrict__ b1g,  const float* __restrict__ b2g,
    const float* __restrict__ tmask,const float* __restrict__ onehots,
    const float* __restrict__ WALL1,const float* __restrict__ WALL2,
    float* __restrict__ H1t,        float* __restrict__ H2t,
    float* __restrict__ Wh,         const float* __restrict__ XST,
    int* __restrict__ cnts,         float* __restrict__ outp)
{
  const int p    = blockIdx.x;
  const int tid  = threadIdx.x;
  const int wave = tid >> 6, lane = tid & 63;
  const int bg4  = (lane & 15) * 4;
  const int cg2  = (lane >> 4) * 2;

  __shared__ float WL1[463*CB];
  __shared__ float WL2[863*CB];
  __shared__ float part[NWAVE][CB][64];
  __shared__ float gred[CB][64];
  __shared__ float cs1[2][64], cs2[2][64];
  __shared__ float bs1[CB], bs2[CB];
  __shared__ float WwinS[30*400];
  __shared__ float onehS[UU*DD];
  __shared__ float tmaskS[UU];
  __shared__ float hbuf[HIDN];
  __shared__ float pw[30];
  __shared__ float kap[KK];
  __shared__ float phiS[UU];

  for (int idx = tid; idx < 463*CB; idx += THR) WL1[idx] = WALL1[p*463*CB + idx];
  for (int idx = tid; idx < 863*CB; idx += THR) WL2[idx] = WALL2[p*863*CB + idx];
  if (tid < CB){ int q = tid>>1, u = tid&1; int j = 2*p+u;
    bs1[tid] = b1g[q*HIDN + j]; bs2[tid] = b2g[q*HIDN + j]; }
  if (tid < 128){ cs1[tid>>6][tid&63] = 0.f; cs2[tid>>6][tid&63] = 0.f; }
  if (p < NWB){
    for (int idx = tid; idx < 30*400; idx += THR) WwinS[idx] = Wwin[idx];
    for (int idx = tid; idx < UU*DD;  idx += THR) onehS[idx] = onehots[p*(UU*DD) + idx];
    if (tid < UU) tmaskS[tid] = tmask[p*UU + tid];
    if (tid < KK) kap[tid] = 0.f;
  }
  __syncthreads();

  for (int i = 0; i <= TT; ++i){
    if (i < TT){
      // ---- GEMV1 step t=i: h1(i-1) rows [0,400), w(i-1) [400,460), x(i) [460,463)
      const float* __restrict__ H1prev = H1t + (size_t)i*SLOT1;
      const float* __restrict__ Whprev = Wh  + (size_t)i*SLOTW;
      float acc[8] = {0,0,0,0,0,0,0,0};
      int k0 = wave*29, k1 = min(k0 + 29, 463);
      { int ka = k0, kb = min(k1, 400);
        if (kb > ka) gemv_seg(H1prev + ka*64, WL1 + ka*CB, kb-ka, bg4, cg2, acc); }
      { int ka = max(k0,400), kb = min(k1, 460);
        if (kb > ka) gemv_seg(Whprev + (ka-400)*64, WL1 + ka*CB, kb-ka, bg4, cg2, acc); }
      { int ka = max(k0,460), kb = k1;
        if (kb > ka) gemv_seg(XST + i*192 + (ka-460)*64, WL1 + ka*CB, kb-ka, bg4, cg2, acc); }
      *(float4*)&part[wave][cg2  ][bg4] = make_float4(acc[0],acc[1],acc[2],acc[3]);
      *(float4*)&part[wave][cg2+1][bg4] = make_float4(acc[4],acc[5],acc[6],acc[7]);
      __syncthreads();
      if (tid < 512){
        int c = tid>>6, b = tid&63; float s = 0.f;
        #pragma unroll
        for (int w16=0; w16<NWAVE; ++w16) s += part[w16][c][b];
        gred[c][b] = s;
      }
      __syncthreads();
      if (tid < 128){
        int u = tid>>6, b = tid&63, j = 2*p + u;
        float gi = gred[0+u][b] + bs1[0+u];
        float gf = gred[2+u][b] + bs1[2+u];
        float gg = gred[4+u][b] + bs1[4+u];
        float go = gred[6+u][b] + bs1[6+u];
        float c_ = sigm(gf)*cs1[u][b] + sigm(gi)*tanhf(gg);
        float h_ = sigm(go)*tanhf(c_);
        cs1[u][b] = c_;
        st_agent(&H1t[(size_t)(i+1)*SLOT1 + j*64 + b], h_);   // publish h1(i)
        if (i == TT-1){ outp[H0F_OFF + b*HIDN + j] = h_; outp[C0F_OFF + b*HIDN + j] = c_; }
      }
      __syncthreads();                       // drain vmcnt: publishes complete
      if (tid == 0){
        __hip_atomic_fetch_add(&cnts[CNTA(i)], 1, __ATOMIC_RELAXED, __HIP_MEMORY_SCOPE_AGENT);
        if (p == MA_BLK){                    // master A: release before GEMV2
          while (ld_agent_i(&cnts[CNTA(i)]) < PBLK) __builtin_amdgcn_s_sleep(2);
          #pragma unroll
          for (int g=0; g<8; ++g) st_agent_i(&cnts[RELA(g)], i+1);
        }
      }
    }

    if (i >= 1){
      // ---- GEMV2 step t2=i-1: h1(i-1) [0,400), h2(i-2) [400,800), w(i-1) [800,860), x [860,863)
      const int t2 = i - 1;
      const float* __restrict__ H1cur = H1t + (size_t)i*SLOT1;
      const float* __restrict__ H2pp  = H2t + (size_t)(i-1)*SLOT1;
      const float* __restrict__ Whcur = Wh  + (size_t)i*SLOTW;
      float acc[8] = {0,0,0,0,0,0,0,0};
      int k0 = wave*54, k1 = min(k0 + 54, 863);
      { int ka = k0, kb = min(k1, 400);
        if (kb > ka) gemv_seg(H1cur + ka*64, WL2 + ka*CB, kb-ka, bg4, cg2, acc); }
      { int ka = max(k0,400), kb = min(k1, 800);
        if (kb > ka) gemv_seg(H2pp + (ka-400)*64, WL2 + ka*CB, kb-ka, bg4, cg2, acc); }
      { int ka = max(k0,800), kb = min(k1, 860);
        if (kb > ka) gemv_seg(Whcur + (ka-800)*64, WL2 + ka*CB, kb-ka, bg4, cg2, acc); }
      { int ka = max(k0,860), kb = k1;
        if (kb > ka) gemv_seg(XST + t2*192 + (ka-860)*64, WL2 + ka*CB, kb-ka, bg4, cg2, acc); }
      __syncthreads();
      *(float4*)&part[wave][cg2  ][bg4] = make_float4(acc[0],acc[1],acc[2],acc[3]);
      *(float4*)&part[wave][cg2+1][bg4] = make_float4(acc[4],acc[5],acc[6],acc[7]);
      __syncthreads();
      if (tid < 512){
        int c = tid>>6, b = tid&63; float s = 0.f;
        #pragma unroll
        for (int w16=0; w16<NWAVE; ++w16) s += part[w16][c][b];
        gred[c][b] = s;
      }
      __syncthreads();
      if (tid < 128){
        int u = tid>>6, b = tid&63, j = 2*p + u;
        float gi = gred[0+u][b] + bs2[0+u];
        float gf = gred[2+u][b] + bs2[2+u];
        float gg = gred[4+u][b] + bs2[4+u];
        float go = gred[6+u][b] + bs2[6+u];
        float c_ = sigm(gf)*cs2[u][b] + sigm(gi)*tanhf(gg);
        float h_ = sigm(go)*tanhf(c_);
        cs2[u][b] = c_;
        st_agent(&H2t[(size_t)i*SLOT1 + j*64 + b], h_);       // publish h2(i-1)
        if (i == TT){ outp[H1F_OFF + b*HIDN + j] = h_; outp[C1F_OFF + b*HIDN + j] = c_; }
      }
    }

    // ---- window for step t=i (blocks 0..63, one batch each)
    if (p < NWB && i < TT){
      const int b = p;
      if (tid == 0){
        wait_ge<4>(&cnts[RELA(p>>3)], i+1);
        __builtin_amdgcn_fence(__ATOMIC_ACQUIRE, "agent");
      }
      __syncthreads();
      const float* __restrict__ H1now = H1t + (size_t)(i+1)*SLOT1;
      for (int k = tid; k < HIDN; k += THR) hbuf[k] = H1now[k*64 + b];
      __syncthreads();
      if (tid < 480){
        int j = tid >> 4, l = tid & 15;
        float s = 0.f;
        for (int k = l; k < HIDN; k += 16) s = fmaf(hbuf[k], WwinS[j*HIDN + k], s);
        s += __shfl_down(s, 8, 16);
        s += __shfl_down(s, 4, 16);
        s += __shfl_down(s, 2, 16);
        s += __shfl_down(s, 1, 16);
        if (l == 0) pw[j] = expf(s + bwin[j]);
      }
      __syncthreads();
      if (tid < KK) kap[tid] += pw[20 + tid];
      __syncthreads();
      if (tid < UU){
        float u = (float)tid, s = 0.f;
        #pragma unroll
        for (int q = 0; q < KK; ++q){
          float d = kap[q] - u;
          s = fmaf(pw[q], expf(-pw[KK+q]*d*d), s);
        }
        s *= tmaskS[tid];
        phiS[tid] = s;
        if (i == TT-1) outp[PHI_OFF + b*UU + tid] = s;
      }
      __syncthreads();
      if (tid < DD){
        float s = 0.f;
        for (int u = 0; u < UU; ++u) s = fmaf(phiS[u], onehS[u*DD + tid], s);
        st_agent(&Wh[(size_t)(i+1)*SLOTW + tid*64 + b], s);   // publish w(i)
        if (i == TT-1) outp[WF_OFF + b*DD + tid] = s;
      }
      if (tid < KK && i == TT-1) outp[KAPPA_OFF + b*KK + tid] = kap[tid];
    }

    // ---- barrier M: h1(i), h2(i-1), w(i) all published
    if (i < TT){
      __syncthreads();                       // drain vmcnt (w / h2 publishes)
      if (tid == 0){
        __hip_atomic_fetch_add(&cnts[CNTM(i)], 1, __ATOMIC_RELAXED, __HIP_MEMORY_SCOPE_AGENT);
        if (p == MM_BLK){
          while (ld_agent_i(&cnts[CNTM(i)]) < PBLK) __builtin_amdgcn_s_sleep(2);
          #pragma unroll
          for (int g=0; g<8; ++g) st_agent_i(&cnts[RELM(g)], i+1);
        } else {
          wait_ge<4>(&cnts[RELM(p & 7)], i+1);
        }
        __builtin_amdgcn_fence(__ATOMIC_ACQUIRE, "agent");
      }
      __syncthreads();
    }
  }
}

// ---------- FC + heads: one block per timestep ----------
__global__ __launch_bounds__(128) void fc2_kernel(
    const float* __restrict__ H1t, const float* __restrict__ H2t,
    const float* __restrict__ WfcT, const float* __restrict__ bfc,
    float* __restrict__ outp)
{
  const int t   = blockIdx.x;
  const int tid = threadIdx.x;
  __shared__ float Xs[8][64];
  __shared__ float OUT[FCOUT][65];
  float acc[64];
  #pragma unroll
  for (int b=0;b<64;++b) acc[b]=0.f;
  const float* __restrict__ base1 = H1t + (size_t)(t+1)*SLOT1;
  const float* __restrict__ base2 = H2t + (size_t)(t+1)*SLOT1;

  for (int kb=0; kb<100; ++kb){
    __syncthreads();
    #pragma unroll
    for (int e=0;e<4;++e){
      int idx = e*128 + tid;
      int row = idx>>6, b = idx&63;
      int k = kb*8 + row;
      Xs[row][b] = (k<400) ? base1[k*64+b] : base2[(k-400)*64+b];
    }
    __syncthreads();
    if (tid < FCOUT){
      #pragma unroll
      for (int kk=0;kk<8;++kk){
        float wv = WfcT[(kb*8+kk)*FCOUT + tid];
        #pragma unroll
        for (int b4=0;b4<16;++b4){
          float4 xv = *(const float4*)&Xs[kk][b4*4];
          acc[b4*4+0] = fmaf(wv, xv.x, acc[b4*4+0]);
          acc[b4*4+1] = fmaf(wv, xv.y, acc[b4*4+1]);
          acc[b4*4+2] = fmaf(wv, xv.z, acc[b4*4+2]);
          acc[b4*4+3] = fmaf(wv, xv.w, acc[b4*4+3]);
        }
      }
    }
  }
  if (tid < FCOUT){
    float bj = bfc[tid];
    #pragma unroll
    for (int b=0;b<64;++b) OUT[tid][b] = acc[b] + bj;
  }
  __syncthreads();
  if (tid < 64){
    const int b = tid;
    const size_t pos = (size_t)b*TT + t;
    for (int j=0;j<40;++j) outp[MU_OFF  + pos*40 + j] = OUT[j][b];
    for (int j=0;j<40;++j) outp[SIG_OFF + pos*40 + j] = OUT[40+j][b];
    float m = -1e30f;
    for (int q=0;q<20;++q) m = fmaxf(m, OUT[80+q][b]);
    float e[20], s=0.f;
    for (int q=0;q<20;++q){ e[q]=expf(OUT[80+q][b]-m); s+=e[q]; }
    float inv = 1.f/s;
    for (int q=0;q<20;++q) outp[PI_OFF  + pos*20 + q] = e[q]*inv;
    for (int q=0;q<20;++q) outp[RHO_OFF + pos*20 + q] = tanhf(OUT[100+q][b]);
    outp[EOS_OFF + pos] = 1.0f/(1.0f + expf(OUT[120][b]));
  }
}

extern "C" void kernel_launch(void* const* d_in, const int* in_sizes, int n_in,
                              void* d_out, int out_size, void* d_ws, size_t ws_size,
                              hipStream_t stream){
  (void)in_sizes; (void)n_in; (void)out_size; (void)ws_size;
  const float* strokes = (const float*)d_in[0];
  const float* onehots = (const float*)d_in[1];
  const float* tmask   = (const float*)d_in[2];
  const float* Wih1    = (const float*)d_in[3];
  const float* Whh1    = (const float*)d_in[4];
  const float* b1      = (const float*)d_in[5];
  const float* Wwin    = (const float*)d_in[6];
  const float* bwin    = (const float*)d_in[7];
  const float* Wih2    = (const float*)d_in[8];
  const float* Whh2    = (const float*)d_in[9];
  const float* b2      = (const float*)d_in[10];
  const float* Wfc     = (const float*)d_in[11];
  const float* bfc     = (const float*)d_in[12];

  float* ws    = (float*)d_ws;
  float* outp  = (float*)d_out;
  float* H1t   = ws + WS_H1T;
  float* H2t   = ws + WS_H2T;
  float* Wh    = ws + WS_WHT;
  float* XST   = ws + WS_XST;
  float* WALL1 = ws + WS_WALL1;
  float* WALL2 = ws + WS_WALL2;
  float* WfcT  = ws + WS_WFCT;
  int*   cnts  = (int*)(ws + WS_CNT);

  hipLaunchKernelGGL(prep_init, dim3((TT*3*64 + 255)/256), dim3(256), 0, stream,
                     onehots, strokes, H1t, H2t, Wh, XST, cnts);
  hipLaunchKernelGGL(prep_wall, dim3((2121600 + 255)/256), dim3(256), 0, stream,
                     Wih1, Whh1, Wih2, Whh2, WALL1, WALL2);
  hipLaunchKernelGGL(prep_wfc, dim3((FCIN*FCOUT + 255)/256), dim3(256), 0, stream,
                     Wfc, WfcT);

  hipLaunchKernelGGL(recurrent_kernel, dim3(PBLK), dim3(THR), 0, stream,
                     Wwin, bwin, b1, b2, tmask, onehots, WALL1, WALL2,
                     H1t, H2t, Wh, XST, cnts, outp);

  hipLaunchKernelGGL(fc2_kernel, dim3(TT), dim3(128), 0, stream,
                     H1t, H2t, WfcT, bfc, outp);
}

// Round 6
// 16571.567 us; speedup vs baseline: 12.2718x; 1.2578x over previous
//
#include <hip/hip_runtime.h>
#include <hip/hip_bf16.h>
#include <math.h>

#define HIDN 400
#define KK   10
#define UU   64
#define DD   60
#define TT   600
#define BB   64
#define FCIN 800
#define FCOUT 121

#define PBLK 200      // persistent blocks (1 per CU via LDS; 200 <= 256 CUs)
#define NWB  64       // window duty on blocks 0..63 (one batch each)
#define THR  1024     // 16 waves
#define NWAVE 16
#define CB   8        // gate-columns per block per LSTM (2 hidden units)

#define SLOT1 25600   // 400*64
#define SLOTW 3840    // 60*64

// ---- d_out offsets (floats) ----
#define PI_OFF    0
#define MU_OFF    768000
#define SIG_OFF   2304000
#define RHO_OFF   3840000
#define EOS_OFF   4608000
#define WF_OFF    4646400
#define KAPPA_OFF 4650240
#define PHI_OFF   4650880
#define H0F_OFF   4654976
#define C0F_OFF   4680576
#define H1F_OFF   4706176
#define C1F_OFF   4731776

// ---- workspace offsets (floats) ----
#define WS_H1T   0                  // 601*25600
#define WS_H2T   15385600           // 601*25600
#define WS_WHT   30771200           // 601*3840
#define WS_XST   33079040           // 600*3*64
#define WS_WALL1 33194240           // 200*463*8
#define WS_WALL2 33935040           // 200*863*8
#define WS_WFCT  35315840           // 800*121
#define WS_CNT   35412640           // 7424 ints
// total = 35,420,064 floats = 141.68 MB (<= round-5 footprint)

// ---- barrier counters: modulo-8 step window, 64B line per (step,group) ----
// groups of 8 arrivals each; target for step i is 8*((i>>3)+1) (monotone, no reset)
#define CAI(i,g) ((((i)&7)*25+(g))*16)            // h1 arrivals: 25 groups (g=p>>3)
#define CWI(i,g) (3200 + (((i)&7)*8+(g))*16)      // w arrivals: 8 groups (g=b>>3)
#define CHI(i,g) (4224 + (((i)&7)*25+(g))*16)     // h2 arrivals: 25 groups
#define CNT_INTS 7424
#define TGT(i)   ((((i)>>3)+1)*8)

__device__ __forceinline__ float sigm(float x){ return 1.0f/(1.0f + expf(-x)); }

__device__ __forceinline__ void st_agent(float* p, float v){
  __hip_atomic_store(p, v, __ATOMIC_RELAXED, __HIP_MEMORY_SCOPE_AGENT);
}
__device__ __forceinline__ int ld_agent_i(const int* p){
  return __hip_atomic_load(p, __ATOMIC_RELAXED, __HIP_MEMORY_SCOPE_AGENT);
}
__device__ __forceinline__ void arrive(int* p){
  __hip_atomic_fetch_add(p, 1, __ATOMIC_RELAXED, __HIP_MEMORY_SCOPE_AGENT);
}
__device__ __forceinline__ void spin_ge(const int* w, int tgt){
  if (ld_agent_i(w) >= tgt) return;
  do { __builtin_amdgcn_s_sleep(1); } while (ld_agent_i(w) < tgt);
}

// ---------- prep ----------
__global__ void prep_init(const float* __restrict__ onehots, const float* __restrict__ strokes,
                          float* __restrict__ H1t, float* __restrict__ H2t,
                          float* __restrict__ Wh,  float* __restrict__ XST,
                          int* __restrict__ cnts){
  int idx = blockIdx.x*blockDim.x + threadIdx.x;
  if (idx < SLOT1){ H1t[idx] = 0.f; H2t[idx] = 0.f; }
  if (idx < SLOTW){
    int d = idx >> 6, b = idx & 63;
    Wh[idx] = onehots[b*(UU*DD) + d];            // onehots[b, u=0, d]
  }
  if (idx < TT*3*64){
    int t = idx/192, rem = idx%192, comp = rem/64, b = rem%64;
    XST[idx] = strokes[(b*TT + t)*3 + comp];
  }
  if (idx < CNT_INTS) cnts[idx] = 0;
}

// ---------- weight reorder ----------
// block p owns hidden units {2p,2p+1}; col c = 2*q + (j&1), gates q: 0=i,1=f,2=g,3=o
// WALL1 rows: [0,400)=h1, [400,460)=w, [460,463)=x
// WALL2 rows: [0,400)=h1, [400,800)=h2, [800,860)=w, [860,863)=x
__global__ void prep_wall(const float* __restrict__ Wih1, const float* __restrict__ Whh1,
                          const float* __restrict__ Wih2, const float* __restrict__ Whh2,
                          float* __restrict__ WALL1, float* __restrict__ WALL2){
  int idx = blockIdx.x*blockDim.x + threadIdx.x;
  if (idx < 640000){                       // W_hh1 (1600,400)
    int g = idx/400, k = idx%400;
    int q = g/400, j = g%400, p = j>>1, c = 2*q + (j&1);
    WALL1[(p*463 + k)*CB + c] = Whh1[idx];
  } else if (idx < 740800){                // W_ih1 (1600,63)
    int s = idx - 640000;
    int g = s/63, col = s%63;
    int q = g/400, j = g%400, p = j>>1, c = 2*q + (j&1);
    int r = (col < 3) ? (460 + col) : (400 + col - 3);
    WALL1[(p*463 + r)*CB + c] = Wih1[s];
  } else if (idx < 1380800){               // W_hh2 (1600,400)
    int s = idx - 740800;
    int g = s/400, k = s%400;
    int q = g/400, j = g%400, p = j>>1, c = 2*q + (j&1);
    WALL2[(p*863 + 400 + k)*CB + c] = Whh2[s];
  } else if (idx < 2121600){               // W_ih2 (1600,463)
    int s = idx - 1380800;
    int g = s/463, col = s%463;
    int q = g/400, j = g%400, p = j>>1, c = 2*q + (j&1);
    int r = (col<3) ? (860+col) : (col<63 ? (800+col-3) : (col-63));
    WALL2[(p*863 + r)*CB + c] = Wih2[s];
  }
}

__global__ void prep_wfc(const float* __restrict__ Wfc, float* __restrict__ WfcT){
  int idx = blockIdx.x*blockDim.x + threadIdx.x;
  if (idx >= FCIN*FCOUT) return;
  int k = idx / FCOUT, j = idx - k*FCOUT;
  WfcT[idx] = Wfc[j*FCIN + k];
}

// ---------- GEMV segment ----------
__device__ __forceinline__ void gemv_seg(const float* __restrict__ x,
                                         const float* __restrict__ w,
                                         int n, int bg4, int cg2, float acc[8]){
  #pragma unroll 4
  for (int k=0;k<n;++k){
    const float4 xv = *(const float4*)(x + k*64 + bg4);
    const float2 wv = *(const float2*)(w + k*CB + cg2);
    acc[0] = fmaf(wv.x, xv.x, acc[0]);
    acc[1] = fmaf(wv.x, xv.y, acc[1]);
    acc[2] = fmaf(wv.x, xv.z, acc[2]);
    acc[3] = fmaf(wv.x, xv.w, acc[3]);
    acc[4] = fmaf(wv.y, xv.x, acc[4]);
    acc[5] = fmaf(wv.y, xv.y, acc[5]);
    acc[6] = fmaf(wv.y, xv.z, acc[6]);
    acc[7] = fmaf(wv.y, xv.w, acc[7]);
  }
}

// ---------- persistent recurrent kernel ----------
__global__ __launch_bounds__(THR) void recurrent_kernel(
    const float* __restrict__ Wwin, const float* __restrict__ bwin,
    const float* __restrict__ b1g,  const float* __restrict__ b2g,
    const float* __restrict__ tmask,const float* __restrict__ onehots,
    const float* __restrict__ WALL1,const float* __restrict__ WALL2,
    float* __restrict__ H1t,        float* __restrict__ H2t,
    float* __restrict__ Wh,         const float* __restrict__ XST,
    int* __restrict__ cnts,         float* __restrict__ outp)
{
  const int p    = blockIdx.x;
  const int tid  = threadIdx.x;
  const int wave = tid >> 6, lane = tid & 63;
  const int bg4  = (lane & 15) * 4;
  const int cg2  = (lane >> 4) * 2;

  __shared__ float WL1[463*CB];
  __shared__ float WL2[863*CB];
  __shared__ float part[NWAVE][CB][64];
  __shared__ float gred[CB][64];
  __shared__ float cs1[2][64], cs2[2][64];
  __shared__ float bs1[CB], bs2[CB];
  __shared__ float WwinS[30*400];
  __shared__ float onehS[UU*DD];
  __shared__ float tmaskS[UU];
  __shared__ float hbuf[HIDN];
  __shared__ float pw[30];
  __shared__ float kap[KK];
  __shared__ float phiS[UU];

  for (int idx = tid; idx < 463*CB; idx += THR) WL1[idx] = WALL1[p*463*CB + idx];
  for (int idx = tid; idx < 863*CB; idx += THR) WL2[idx] = WALL2[p*863*CB + idx];
  if (tid < CB){ int q = tid>>1, u = tid&1; int j = 2*p+u;
    bs1[tid] = b1g[q*HIDN + j]; bs2[tid] = b2g[q*HIDN + j]; }
  if (tid < 128){ cs1[tid>>6][tid&63] = 0.f; cs2[tid>>6][tid&63] = 0.f; }
  if (p < NWB){
    for (int idx = tid; idx < 30*400; idx += THR) WwinS[idx] = Wwin[idx];
    for (int idx = tid; idx < UU*DD;  idx += THR) onehS[idx] = onehots[p*(UU*DD) + idx];
    if (tid < UU) tmaskS[tid] = tmask[p*UU + tid];
    if (tid < KK) kap[tid] = 0.f;
  }
  __syncthreads();

  for (int i = 0; i <= TT; ++i){
    // ---- pre-iter wait: h1(i-1) (CA) and w(i-1) (CW) ----
    if (i >= 1){
      if (tid < 25)                 spin_ge(&cnts[CAI(i-1, tid)],    TGT(i-1));
      else if (tid >= 32 && tid < 40) spin_ge(&cnts[CWI(i-1, tid-32)], TGT(i-1));
      asm volatile("" ::: "memory");
      __syncthreads();
    }

    if (i < TT){
      // ---- GEMV1 step t=i: h1(i-1) rows [0,400), w(i-1) [400,460), x(i) [460,463)
      const float* __restrict__ H1prev = H1t + (size_t)i*SLOT1;
      const float* __restrict__ Whprev = Wh  + (size_t)i*SLOTW;
      float acc[8] = {0,0,0,0,0,0,0,0};
      int k0 = wave*29, k1 = min(k0 + 29, 463);
      { int ka = k0, kb = min(k1, 400);
        if (kb > ka) gemv_seg(H1prev + ka*64, WL1 + ka*CB, kb-ka, bg4, cg2, acc); }
      { int ka = max(k0,400), kb = min(k1, 460);
        if (kb > ka) gemv_seg(Whprev + (ka-400)*64, WL1 + ka*CB, kb-ka, bg4, cg2, acc); }
      { int ka = max(k0,460), kb = k1;
        if (kb > ka) gemv_seg(XST + i*192 + (ka-460)*64, WL1 + ka*CB, kb-ka, bg4, cg2, acc); }
      *(float4*)&part[wave][cg2  ][bg4] = make_float4(acc[0],acc[1],acc[2],acc[3]);
      *(float4*)&part[wave][cg2+1][bg4] = make_float4(acc[4],acc[5],acc[6],acc[7]);
      __syncthreads();
      if (tid < 512){
        int c = tid>>6, b = tid&63; float s = 0.f;
        #pragma unroll
        for (int w16=0; w16<NWAVE; ++w16) s += part[w16][c][b];
        gred[c][b] = s;
      }
      __syncthreads();
      if (tid < 128){
        int u = tid>>6, b = tid&63, j = 2*p + u;
        float gi = gred[0+u][b] + bs1[0+u];
        float gf = gred[2+u][b] + bs1[2+u];
        float gg = gred[4+u][b] + bs1[4+u];
        float go = gred[6+u][b] + bs1[6+u];
        float c_ = sigm(gf)*cs1[u][b] + sigm(gi)*tanhf(gg);
        float h_ = sigm(go)*tanhf(c_);
        cs1[u][b] = c_;
        st_agent(&H1t[(size_t)(i+1)*SLOT1 + j*64 + b], h_);   // publish h1(i)
        if (i == TT-1){ outp[H0F_OFF + b*HIDN + j] = h_; outp[C0F_OFF + b*HIDN + j] = c_; }
      }
      __syncthreads();                       // drains vmcnt: publishes complete
      if (tid == 0) arrive(&cnts[CAI(i, p>>3)]);
    }

    // ---- window for step t=i (blocks 0..63) — BEFORE our own GEMV2 ----
    if (p < NWB && i < TT){
      const int b = p;
      if (tid < 25) spin_ge(&cnts[CAI(i, tid)], TGT(i));
      asm volatile("" ::: "memory");
      __syncthreads();
      const float* __restrict__ H1now = H1t + (size_t)(i+1)*SLOT1;
      for (int k = tid; k < HIDN; k += THR) hbuf[k] = H1now[k*64 + b];
      __syncthreads();
      if (tid < 480){
        int j = tid >> 4, l = tid & 15;
        float s = 0.f;
        for (int k = l; k < HIDN; k += 16) s = fmaf(hbuf[k], WwinS[j*HIDN + k], s);
        s += __shfl_down(s, 8, 16);
        s += __shfl_down(s, 4, 16);
        s += __shfl_down(s, 2, 16);
        s += __shfl_down(s, 1, 16);
        if (l == 0) pw[j] = expf(s + bwin[j]);
      }
      __syncthreads();
      if (tid < KK) kap[tid] += pw[20 + tid];
      __syncthreads();
      if (tid < UU){
        float u = (float)tid, s = 0.f;
        #pragma unroll
        for (int q = 0; q < KK; ++q){
          float d = kap[q] - u;
          s = fmaf(pw[q], expf(-pw[KK+q]*d*d), s);
        }
        s *= tmaskS[tid];
        phiS[tid] = s;
        if (i == TT-1) outp[PHI_OFF + b*UU + tid] = s;
      }
      __syncthreads();
      if (tid < DD){
        float s = 0.f;
        for (int u = 0; u < UU; ++u) s = fmaf(phiS[u], onehS[u*DD + tid], s);
        st_agent(&Wh[(size_t)(i+1)*SLOTW + tid*64 + b], s);   // publish w(i)
        if (i == TT-1) outp[WF_OFF + b*DD + tid] = s;
      }
      if (tid < KK && i == TT-1) outp[KAPPA_OFF + b*KK + tid] = kap[tid];
      __syncthreads();                       // drain w publish
      if (tid == 0) arrive(&cnts[CWI(i, p>>3)]);
    }

    if (i >= 1){
      // ---- pre-GEMV2 wait: h2(i-2) ----
      if (i >= 2){
        if (tid < 25) spin_ge(&cnts[CHI(i-2, tid)], TGT(i-2));
        asm volatile("" ::: "memory");
        __syncthreads();
      }
      // ---- GEMV2 step t2=i-1: h1(i-1) [0,400), h2(i-2) [400,800), w(i-1) [800,860), x [860,863)
      const int t2 = i - 1;
      const float* __restrict__ H1cur = H1t + (size_t)i*SLOT1;
      const float* __restrict__ H2pp  = H2t + (size_t)(i-1)*SLOT1;
      const float* __restrict__ Whcur = Wh  + (size_t)i*SLOTW;
      float acc[8] = {0,0,0,0,0,0,0,0};
      int k0 = wave*54, k1 = min(k0 + 54, 863);
      { int ka = k0, kb = min(k1, 400);
        if (kb > ka) gemv_seg(H1cur + ka*64, WL2 + ka*CB, kb-ka, bg4, cg2, acc); }
      { int ka = max(k0,400), kb = min(k1, 800);
        if (kb > ka) gemv_seg(H2pp + (ka-400)*64, WL2 + ka*CB, kb-ka, bg4, cg2, acc); }
      { int ka = max(k0,800), kb = min(k1, 860);
        if (kb > ka) gemv_seg(Whcur + (ka-800)*64, WL2 + ka*CB, kb-ka, bg4, cg2, acc); }
      { int ka = max(k0,860), kb = k1;
        if (kb > ka) gemv_seg(XST + t2*192 + (ka-860)*64, WL2 + ka*CB, kb-ka, bg4, cg2, acc); }
      __syncthreads();                       // part free (prior readers done)
      *(float4*)&part[wave][cg2  ][bg4] = make_float4(acc[0],acc[1],acc[2],acc[3]);
      *(float4*)&part[wave][cg2+1][bg4] = make_float4(acc[4],acc[5],acc[6],acc[7]);
      __syncthreads();
      if (tid < 512){
        int c = tid>>6, b = tid&63; float s = 0.f;
        #pragma unroll
        for (int w16=0; w16<NWAVE; ++w16) s += part[w16][c][b];
        gred[c][b] = s;
      }
      __syncthreads();
      if (tid < 128){
        int u = tid>>6, b = tid&63, j = 2*p + u;
        float gi = gred[0+u][b] + bs2[0+u];
        float gf = gred[2+u][b] + bs2[2+u];
        float gg = gred[4+u][b] + bs2[4+u];
        float go = gred[6+u][b] + bs2[6+u];
        float c_ = sigm(gf)*cs2[u][b] + sigm(gi)*tanhf(gg);
        float h_ = sigm(go)*tanhf(c_);
        cs2[u][b] = c_;
        st_agent(&H2t[(size_t)i*SLOT1 + j*64 + b], h_);       // publish h2(i-1)
        if (i == TT){ outp[H1F_OFF + b*HIDN + j] = h_; outp[C1F_OFF + b*HIDN + j] = c_; }
      }
      if (i < TT){
        __syncthreads();                     // drain h2 publish
        if (tid == 0) arrive(&cnts[CHI(i-1, p>>3)]);
      }
    }
  }
}

// ---------- FC + heads: one block per timestep ----------
__global__ __launch_bounds__(128) void fc2_kernel(
    const float* __restrict__ H1t, const float* __restrict__ H2t,
    const float* __restrict__ WfcT, const float* __restrict__ bfc,
    float* __restrict__ outp)
{
  const int t   = blockIdx.x;
  const int tid = threadIdx.x;
  __shared__ float Xs[8][64];
  __shared__ float OUT[FCOUT][65];
  float acc[64];
  #pragma unroll
  for (int b=0;b<64;++b) acc[b]=0.f;
  const float* __restrict__ base1 = H1t + (size_t)(t+1)*SLOT1;
  const float* __restrict__ base2 = H2t + (size_t)(t+1)*SLOT1;

  for (int kb=0; kb<100; ++kb){
    __syncthreads();
    #pragma unroll
    for (int e=0;e<4;++e){
      int idx = e*128 + tid;
      int row = idx>>6, b = idx&63;
      int k = kb*8 + row;
      Xs[row][b] = (k<400) ? base1[k*64+b] : base2[(k-400)*64+b];
    }
    __syncthreads();
    if (tid < FCOUT){
      #pragma unroll
      for (int kk=0;kk<8;++kk){
        float wv = WfcT[(kb*8+kk)*FCOUT + tid];
        #pragma unroll
        for (int b4=0;b4<16;++b4){
          float4 xv = *(const float4*)&Xs[kk][b4*4];
          acc[b4*4+0] = fmaf(wv, xv.x, acc[b4*4+0]);
          acc[b4*4+1] = fmaf(wv, xv.y, acc[b4*4+1]);
          acc[b4*4+2] = fmaf(wv, xv.z, acc[b4*4+2]);
          acc[b4*4+3] = fmaf(wv, xv.w, acc[b4*4+3]);
        }
      }
    }
  }
  if (tid < FCOUT){
    float bj = bfc[tid];
    #pragma unroll
    for (int b=0;b<64;++b) OUT[tid][b] = acc[b] + bj;
  }
  __syncthreads();
  if (tid < 64){
    const int b = tid;
    const size_t pos = (size_t)b*TT + t;
    for (int j=0;j<40;++j) outp[MU_OFF  + pos*40 + j] = OUT[j][b];
    for (int j=0;j<40;++j) outp[SIG_OFF + pos*40 + j] = OUT[40+j][b];
    float m = -1e30f;
    for (int q=0;q<20;++q) m = fmaxf(m, OUT[80+q][b]);
    float e[20], s=0.f;
    for (int q=0;q<20;++q){ e[q]=expf(OUT[80+q][b]-m); s+=e[q]; }
    float inv = 1.f/s;
    for (int q=0;q<20;++q) outp[PI_OFF  + pos*20 + q] = e[q]*inv;
    for (int q=0;q<20;++q) outp[RHO_OFF + pos*20 + q] = tanhf(OUT[100+q][b]);
    outp[EOS_OFF + pos] = 1.0f/(1.0f + expf(OUT[120][b]));
  }
}

extern "C" void kernel_launch(void* const* d_in, const int* in_sizes, int n_in,
                              void* d_out, int out_size, void* d_ws, size_t ws_size,
                              hipStream_t stream){
  (void)in_sizes; (void)n_in; (void)out_size; (void)ws_size;
  const float* strokes = (const float*)d_in[0];
  const float* onehots = (const float*)d_in[1];
  const float* tmask   = (const float*)d_in[2];
  const float* Wih1    = (const float*)d_in[3];
  const float* Whh1    = (const float*)d_in[4];
  const float* b1      = (const float*)d_in[5];
  const float* Wwin    = (const float*)d_in[6];
  const float* bwin    = (const float*)d_in[7];
  const float* Wih2    = (const float*)d_in[8];
  const float* Whh2    = (const float*)d_in[9];
  const float* b2      = (const float*)d_in[10];
  const float* Wfc     = (const float*)d_in[11];
  const float* bfc     = (const float*)d_in[12];

  float* ws    = (float*)d_ws;
  float* outp  = (float*)d_out;
  float* H1t   = ws + WS_H1T;
  float* H2t   = ws + WS_H2T;
  float* Wh    = ws + WS_WHT;
  float* XST   = ws + WS_XST;
  float* WALL1 = ws + WS_WALL1;
  float* WALL2 = ws + WS_WALL2;
  float* WfcT  = ws + WS_WFCT;
  int*   cnts  = (int*)(ws + WS_CNT);

  hipLaunchKernelGGL(prep_init, dim3((TT*3*64 + 255)/256), dim3(256), 0, stream,
                     onehots, strokes, H1t, H2t, Wh, XST, cnts);
  hipLaunchKernelGGL(prep_wall, dim3((2121600 + 255)/256), dim3(256), 0, stream,
                     Wih1, Whh1, Wih2, Whh2, WALL1, WALL2);
  hipLaunchKernelGGL(prep_wfc, dim3((FCIN*FCOUT + 255)/256), dim3(256), 0, stream,
                     Wfc, WfcT);

  hipLaunchKernelGGL(recurrent_kernel, dim3(PBLK), dim3(THR), 0, stream,
                     Wwin, bwin, b1, b2, tmask, onehots, WALL1, WALL2,
                     H1t, H2t, Wh, XST, cnts, outp);

  hipLaunchKernelGGL(fc2_kernel, dim3(TT), dim3(128), 0, stream,
                     H1t, H2t, WfcT, bfc, outp);
}